// Round 2
// baseline (17425.269 us; speedup 1.0000x reference)
//
#include <hip/hip_runtime.h>

// ---------------- problem constants ----------------
#define B_RUNS 500
#define WAYS   5
#define NSUP   25
#define NQ     75
#define NN     100
#define DIM    640
#define TOPK   6
#define KHOP   4
#define NEPOCH 10
#define MAXIT  1000
#define NBLK   B_RUNS

#define CTRL_BYTES  131072

// per-episode layout: feat [NN*DIM] (FT) | A/Inv [NN*NN] f64 | prot [5*DIM] f64 | nrm [NN] f64
__host__ __device__ constexpr size_t ep_bytes(size_t fsz) {
  size_t v = (size_t)NN * DIM * fsz + (size_t)(NN * NN + WAYS * DIM + NN) * 8;
  return ((v + 255) / 256) * 256;
}

__device__ __forceinline__ double wsum64d(double v) {
  #pragma unroll
  for (int off = 32; off > 0; off >>= 1) v += __shfl_xor(v, off, 64);
  return v;
}

// =====================================================================
// Kernel 1: per-episode hops + build_graph^2 + (I-0.7W)^-1 + proto/norms
// fp64 throughout; 100x100 workspace lives in global (Inv region)
// =====================================================================
template <typename FT>
__global__ __launch_bounds__(256) void k1_hops(const float* __restrict__ xs,
                                               const float* __restrict__ xq,
                                               char* __restrict__ wsb) {
  const int b = blockIdx.x;
  char* epb = wsb + CTRL_BYTES + (size_t)b * ep_bytes(sizeof(FT));
  FT* feat     = (FT*)epb;
  double* A    = (double*)(epb + (size_t)NN * DIM * sizeof(FT));  // ends as Inv
  double* prot = A + NN * NN;
  double* nrm  = prot + WAYS * DIM;

  __shared__ double SH[6600];    // 52800 B multi-purpose staging
  __shared__ double nsh[NN], Dsh[NN], rowk[NN], colk[NN];

  const int t  = threadIdx.x;
  const int tx = t & 15, ty = t >> 4;
  int ia[7], ja[7];
  #pragma unroll
  for (int a = 0; a < 7; ++a) { int v = ty + 16 * a; ia[a] = v < NN ? v : NN - 1; }
  #pragma unroll
  for (int a = 0; a < 7; ++a) { int v = tx + 16 * a; ja[a] = v < NN ? v : NN - 1; }

  const float* xsb = xs + (size_t)b * NSUP * DIM;
  const float* xqb = xq + (size_t)b * NQ * DIM;
  for (int e = t; e < NSUP * DIM; e += 256) feat[e] = (FT)xsb[e];
  for (int e = t; e < NQ * DIM; e += 256)  feat[NSUP * DIM + e] = (FT)xqb[e];
  __syncthreads();

  for (int hop = 0; hop < KHOP; ++hop) {
    // ---- C = F F^T in fp64 (7x7 tiles, 16-wide k chunks staged in LDS) ----
    double acc[7][7];
    #pragma unroll
    for (int a = 0; a < 7; ++a)
      #pragma unroll
      for (int c = 0; c < 7; ++c) acc[a][c] = 0.0;
    for (int k0 = 0; k0 < DIM; k0 += 16) {
      for (int e = t; e < NN * 16; e += 256) {
        int r = e >> 4, kk = e & 15;
        SH[kk * NN + r] = (double)feat[r * DIM + k0 + kk];
      }
      __syncthreads();
      #pragma unroll 2
      for (int kk = 0; kk < 16; ++kk) {
        double rv[7], cv[7];
        #pragma unroll
        for (int a = 0; a < 7; ++a) rv[a] = SH[kk * NN + ia[a]];
        #pragma unroll
        for (int c = 0; c < 7; ++c) cv[c] = SH[kk * NN + ja[c]];
        #pragma unroll
        for (int a = 0; a < 7; ++a)
          #pragma unroll
          for (int c = 0; c < 7; ++c) acc[a][c] = fma(rv[a], cv[c], acc[a][c]);
      }
      __syncthreads();
    }
    #pragma unroll
    for (int a = 0; a < 7; ++a)
      #pragma unroll
      for (int c = 0; c < 7; ++c) {
        int i = ty + 16 * a, j = tx + 16 * c;
        if (i < NN && j < NN) A[i * NN + j] = acc[a][c];
      }
    __syncthreads();
    if (t < NN) nsh[t] = A[t * NN + t];
    __syncthreads();
    // A = exp(-10 * max(ni+nj-2c, 0))
    for (int e = t; e < NN * NN; e += 256) {
      int i = e / NN, j = e % NN;
      double d = (nsh[i] + nsh[j]) - 2.0 * A[e];
      d = d > 0.0 ? d : 0.0;
      A[e] = exp(-10.0 * d);
    }
    __syncthreads();
    // ---- top-6 per row (ties -> lowest index, matches lax.top_k) ----
    if (t < NN) {
      unsigned long long m0 = 0ull, m1 = 0ull;
      for (int s = 0; s < TOPK; ++s) {
        double best = -1.0; int bj = 0;
        for (int j = 0; j < NN; ++j) {
          unsigned long long bit = (j < 64) ? ((m0 >> j) & 1ull) : ((m1 >> (j - 64)) & 1ull);
          if (bit) continue;
          double v = A[t * NN + j];
          if (v > best) { best = v; bj = j; }
        }
        if (bj < 64) m0 |= 1ull << bj; else m1 |= 1ull << (bj - 64);
      }
      for (int j = 0; j < NN; ++j) {
        unsigned long long bit = (j < 64) ? ((m0 >> j) & 1ull) : ((m1 >> (j - 64)) & 1ull);
        if (!bit) A[t * NN + j] = 0.0;
      }
    }
    __syncthreads();
    if (t < NN) {
      double s = 0.0;
      for (int j = 0; j < NN; ++j) s += A[t * NN + j];
      Dsh[t] = 1.0 / sqrt(s);
    }
    __syncthreads();
    // L = 0.5 I + 0.5 * (D_j * A * D_i)
    for (int e = t; e < NN * NN; e += 256) {
      int i = e / NN, j = e % NN;
      double w = (Dsh[j] * A[e]) * Dsh[i];
      A[e] = ((i == j) ? 0.5 : 0.0) + 0.5 * w;
    }
    __syncthreads();
    // ---- G = L @ L (registers from global L), then overwrite A ----
    double gg[7][7];
    #pragma unroll
    for (int a = 0; a < 7; ++a)
      #pragma unroll
      for (int c = 0; c < 7; ++c) gg[a][c] = 0.0;
    for (int k = 0; k < NN; ++k) {
      double rv[7], cv[7];
      #pragma unroll
      for (int a = 0; a < 7; ++a) rv[a] = A[ia[a] * NN + k];
      #pragma unroll
      for (int c = 0; c < 7; ++c) cv[c] = A[k * NN + ja[c]];
      #pragma unroll
      for (int a = 0; a < 7; ++a)
        #pragma unroll
        for (int c = 0; c < 7; ++c) gg[a][c] = fma(rv[a], cv[c], gg[a][c]);
    }
    __syncthreads();   // all reads of L done before overwrite
    #pragma unroll
    for (int a = 0; a < 7; ++a)
      #pragma unroll
      for (int c = 0; c < 7; ++c) {
        int i = ty + 16 * a, j = tx + 16 * c;
        if (i < NN && j < NN) A[i * NN + j] = gg[a][c];
      }
    __syncthreads();
    // ---- feat = G @ feat (16-col blocks; G staged in LDS halves) ----
    double* Fb = SH;            // NN*16 = 1600 doubles
    double* Gb = SH + 1600;     // NN*50 = 5000 doubles
    for (int c0 = 0; c0 < DIM; c0 += 16) {
      for (int e = t; e < NN * 16; e += 256) {
        int k = e >> 4, cc = e & 15;
        Fb[e] = (double)feat[k * DIM + c0 + cc];
      }
      double f[7];
      #pragma unroll
      for (int a = 0; a < 7; ++a) f[a] = 0.0;
      for (int kh = 0; kh < 2; ++kh) {
        for (int e = t; e < NN * 50; e += 256) {
          int i = e / 50, kk = e % 50;
          Gb[e] = A[i * NN + kh * 50 + kk];
        }
        __syncthreads();
        for (int kk = 0; kk < 50; ++kk) {
          double fv = Fb[(kh * 50 + kk) * 16 + tx];
          #pragma unroll
          for (int a = 0; a < 7; ++a) f[a] = fma(Gb[ia[a] * 50 + kk], fv, f[a]);
        }
        __syncthreads();
      }
      #pragma unroll
      for (int a = 0; a < 7; ++a) {
        int i = ty + 16 * a;
        if (i < NN) feat[i * DIM + c0 + tx] = (FT)f[a];
      }
      __syncthreads();
    }

    if (hop == KHOP - 1) {
      // ---- W = build_graph(build_graph(G)) in place ----
      for (int rep = 0; rep < 2; ++rep) {
        if (t < NN) A[t * NN + t] = 0.0;
        __syncthreads();
        if (t < NN) {
          double s = 0.0;
          for (int j = 0; j < NN; ++j) s += A[t * NN + j];
          Dsh[t] = 1.0 / sqrt(s);
        }
        __syncthreads();
        for (int e = t; e < NN * NN; e += 256) {
          int i = e / NN, j = e % NN;
          A[e] = (Dsh[j] * A[e]) * Dsh[i];
        }
        __syncthreads();
      }
      // M = I - 0.7*W
      for (int e = t; e < NN * NN; e += 256) {
        int i = e / NN, j = e % NN;
        A[e] = ((i == j) ? 1.0 : 0.0) - 0.7 * A[e];
      }
      __syncthreads();
      // ---- in-place Gauss-Jordan (sweep) inverse, FIXED pivot column ----
      for (int k = 0; k < NN; ++k) {
        if (t < NN) { rowk[t] = A[k * NN + t]; colk[t] = A[t * NN + k]; }
        __syncthreads();
        double pinv = 1.0 / rowk[k];
        for (int e = t; e < NN * NN; e += 256) {
          int i = e / NN, j = e % NN;
          double v;
          if (i == k)      v = (j == k) ? pinv : rowk[j] * pinv;
          else if (j == k) v = -(colk[i] * pinv);           // BUGFIX: was -colk[i]
          else             v = A[e] - colk[i] * (rowk[j] * pinv);
          A[e] = v;
        }
        __syncthreads();
      }
      // proto0 = mean over shots
      for (int e = t; e < WAYS * DIM; e += 256) {
        int w = e / DIM, d = e % DIM;
        double s = 0.0;
        #pragma unroll
        for (int sh = 0; sh < 5; ++sh) s += (double)feat[(w * 5 + sh) * DIM + d];
        prot[e] = s / 5.0;
      }
      // feature norms
      if (t < NN) {
        double s = 0.0;
        for (int k = 0; k < DIM; ++k) {
          double f = (double)feat[t * DIM + k];
          s = fma(f, f, s);
        }
        nrm[t] = s;
      }
    }
  }
}

// =====================================================================
// Kernel 2: persistent lockstep epochs, fp64; global Sinkhorn while-loop
// replicated via per-iteration flags + software grid barrier
// =====================================================================
template <typename FT>
__global__ __launch_bounds__(256, 2) void k2_epochs(const int* __restrict__ ys,
                                                    const int* __restrict__ yq,
                                                    char* __restrict__ wsb,
                                                    float* __restrict__ out) {
  const int b = blockIdx.x;
  char* epb = wsb + CTRL_BYTES + (size_t)b * ep_bytes(sizeof(FT));
  const FT* feat    = (const FT*)epb;
  const double* Inv = (const double*)(epb + (size_t)NN * DIM * sizeof(FT));
  double* prot      = (double*)(Inv + NN * NN);
  const double* nrm = prot + WAYS * DIM;
  unsigned* ctrl   = (unsigned*)wsb;
  unsigned* arrive = ctrl + 0;
  unsigned* abortf = ctrl + 1;
  unsigned* flags  = ctrl + 16;

  __shared__ double Z[NN * WAYS];
  __shared__ double Zn[NN * WAYS];
  __shared__ double protS[WAYS * DIM];
  __shared__ double pn[WAYS];
  __shared__ double ua[NN];
  __shared__ double up[NN];
  __shared__ double csv[WAYS];
  __shared__ int ysS[NSUP];
  __shared__ int redi;
  __shared__ unsigned long long redd;
  __shared__ unsigned flagsh;

  const int t  = threadIdx.x;
  const int wv = t >> 6, ln = t & 63;
  unsigned barc = 0;
  unsigned git  = 0;

  if (t < NSUP) ysS[t] = ys[b * NSUP + t];
  __syncthreads();

  auto sinkhorn = [&](int base, int n, double cval, bool clamp) {
    if (t < n) up[t] = 0.0;
    int it = 1;
    for (;;) {
      __syncthreads();
      if (t == 0) redd = 0ull;
      __syncthreads();
      if (t < n) {
        double u = 0.0;
        #pragma unroll
        for (int w = 0; w < WAYS; ++w) u += Z[(base + t) * WAYS + w];
        ua[t] = u;
        double d = fabs(up[t] - u);
        atomicMax(&redd, (unsigned long long)__double_as_longlong(d));
      }
      __syncthreads();
      if (t == 0) {
        if (__longlong_as_double((long long)redd) > 1e-3 && git < 32000u)
          __hip_atomic_fetch_or(&flags[git], 1u, __ATOMIC_RELAXED, __HIP_MEMORY_SCOPE_AGENT);
      }
      __syncthreads();
      if (t == 0) {
        ++barc;
        unsigned target = barc * (unsigned)NBLK;
        if (__hip_atomic_load(abortf, __ATOMIC_RELAXED, __HIP_MEMORY_SCOPE_AGENT) == 0u) {
          __hip_atomic_fetch_add(arrive, 1u, __ATOMIC_ACQ_REL, __HIP_MEMORY_SCOPE_AGENT);
          long sp = 0;
          while (__hip_atomic_load(arrive, __ATOMIC_ACQUIRE, __HIP_MEMORY_SCOPE_AGENT) < target) {
            __builtin_amdgcn_s_sleep(4);
            if (++sp > 10000000L) {
              __hip_atomic_store(abortf, 1u, __ATOMIC_RELAXED, __HIP_MEMORY_SCOPE_AGENT);
              break;
            }
          }
        }
        flagsh = (git < 32000u)
                   ? __hip_atomic_load(&flags[git], __ATOMIC_RELAXED, __HIP_MEMORY_SCOPE_AGENT)
                   : 0u;
      }
      __syncthreads();
      unsigned go = flagsh;
      ++git;
      if (!(go != 0u && it <= MAXIT)) break;
      // body
      if (t < n) {
        double inv = 1.0 / ua[t];
        #pragma unroll
        for (int w = 0; w < WAYS; ++w) Z[(base + t) * WAYS + w] *= inv;
        up[t] = ua[t];
      }
      __syncthreads();
      if (t < WAYS) {
        double s = 0.0;
        for (int r = 0; r < n; ++r) s += Z[(base + r) * WAYS + t];
        csv[t] = cval / s;
      }
      __syncthreads();
      if (t < n) {
        #pragma unroll
        for (int w = 0; w < WAYS; ++w) Z[(base + t) * WAYS + w] *= csv[w];
      }
      if (clamp) {
        __syncthreads();
        if (t < NSUP) {
          #pragma unroll
          for (int w = 0; w < WAYS; ++w) Z[t * WAYS + w] = (ysS[t] == w) ? 1.0 : 0.0;
        }
      }
      ++it;
    }
    __syncthreads();
  };

  for (int epi = 0; epi <= NEPOCH; ++epi) {
    for (int e = t; e < WAYS * DIM; e += 256) protS[e] = prot[e];
    __syncthreads();
    if (t < WAYS) {
      double s = 0.0;
      for (int k = 0; k < DIM; ++k) { double p = protS[t * DIM + k]; s = fma(p, p, s); }
      pn[t] = s;
    }
    __syncthreads();
    // Pq rows 25..99
    for (int r = NSUP + wv; r < NN; r += 4) {
      double a0 = 0, a1 = 0, a2 = 0, a3 = 0, a4 = 0;
      #pragma unroll
      for (int m = 0; m < DIM / 64; ++m) {
        int k = ln + 64 * m;
        double f = (double)feat[r * DIM + k];
        a0 = fma(f, protS[0 * DIM + k], a0);
        a1 = fma(f, protS[1 * DIM + k], a1);
        a2 = fma(f, protS[2 * DIM + k], a2);
        a3 = fma(f, protS[3 * DIM + k], a3);
        a4 = fma(f, protS[4 * DIM + k], a4);
      }
      a0 = wsum64d(a0); a1 = wsum64d(a1); a2 = wsum64d(a2);
      a3 = wsum64d(a3); a4 = wsum64d(a4);
      if (ln == 0) {
        double nr = nrm[r];
        double d0 = (nr + pn[0]) - 2.0 * a0;
        double d1 = (nr + pn[1]) - 2.0 * a1;
        double d2 = (nr + pn[2]) - 2.0 * a2;
        double d3 = (nr + pn[3]) - 2.0 * a3;
        double d4 = (nr + pn[4]) - 2.0 * a4;
        Z[r * WAYS + 0] = exp(-10.0 * (d0 > 0.0 ? d0 : 0.0));
        Z[r * WAYS + 1] = exp(-10.0 * (d1 > 0.0 ? d1 : 0.0));
        Z[r * WAYS + 2] = exp(-10.0 * (d2 > 0.0 ? d2 : 0.0));
        Z[r * WAYS + 3] = exp(-10.0 * (d3 > 0.0 ? d3 : 0.0));
        Z[r * WAYS + 4] = exp(-10.0 * (d4 > 0.0 ? d4 : 0.0));
      }
    }
    __syncthreads();
    sinkhorn(NSUP, NQ, 15.0, false);

    if (epi == NEPOCH) {
      if (t == 0) redi = 0;
      __syncthreads();
      if (t < NQ) {
        int row = NSUP + t;
        double bv = Z[row * WAYS + 0]; int am = 0;
        #pragma unroll
        for (int w = 1; w < WAYS; ++w) {
          double v = Z[row * WAYS + w];
          if (v > bv) { bv = v; am = w; }
        }
        if (am == yq[b * NQ + t]) atomicAdd(&redi, 1);
      }
      __syncthreads();
      if (t == 0) out[b] = (float)((double)redi / 75.0);
    } else {
      if (t < NSUP) {
        #pragma unroll
        for (int w = 0; w < WAYS; ++w) Z[t * WAYS + w] = (ysS[t] == w) ? 1.0 : 0.0;
      }
      __syncthreads();
      // Zn = Inv @ Z
      for (int r = wv; r < NN; r += 4) {
        double a0 = 0, a1 = 0, a2 = 0, a3 = 0, a4 = 0;
        for (int k = ln; k < NN; k += 64) {
          double iv = Inv[r * NN + k];
          a0 = fma(iv, Z[k * WAYS + 0], a0);
          a1 = fma(iv, Z[k * WAYS + 1], a1);
          a2 = fma(iv, Z[k * WAYS + 2], a2);
          a3 = fma(iv, Z[k * WAYS + 3], a3);
          a4 = fma(iv, Z[k * WAYS + 4], a4);
        }
        a0 = wsum64d(a0); a1 = wsum64d(a1); a2 = wsum64d(a2);
        a3 = wsum64d(a3); a4 = wsum64d(a4);
        if (ln == 0) {
          Zn[r * WAYS + 0] = a0; Zn[r * WAYS + 1] = a1; Zn[r * WAYS + 2] = a2;
          Zn[r * WAYS + 3] = a3; Zn[r * WAYS + 4] = a4;
        }
      }
      __syncthreads();
      for (int e = t; e < NN * WAYS; e += 256) Z[e] = Zn[e];
      __syncthreads();
      sinkhorn(0, NN, 20.0, true);
      if (t < WAYS) {
        double s = 0.0;
        for (int r = 0; r < NN; ++r) s += Z[r * WAYS + t];
        csv[t] = s;
      }
      __syncthreads();
      // proto = 0.4*proto + 0.6*(Z^T feat / colsum)
      for (int d = t; d < DIM; d += 256) {
        double a0 = 0, a1 = 0, a2 = 0, a3 = 0, a4 = 0;
        for (int n = 0; n < NN; ++n) {
          double f = (double)feat[n * DIM + d];
          a0 = fma(Z[n * WAYS + 0], f, a0);
          a1 = fma(Z[n * WAYS + 1], f, a1);
          a2 = fma(Z[n * WAYS + 2], f, a2);
          a3 = fma(Z[n * WAYS + 3], f, a3);
          a4 = fma(Z[n * WAYS + 4], f, a4);
        }
        double o, npv;
        npv = a0 / csv[0]; o = prot[0 * DIM + d]; prot[0 * DIM + d] = 0.4 * o + 0.6 * npv;
        npv = a1 / csv[1]; o = prot[1 * DIM + d]; prot[1 * DIM + d] = 0.4 * o + 0.6 * npv;
        npv = a2 / csv[2]; o = prot[2 * DIM + d]; prot[2 * DIM + d] = 0.4 * o + 0.6 * npv;
        npv = a3 / csv[3]; o = prot[3 * DIM + d]; prot[3 * DIM + d] = 0.4 * o + 0.6 * npv;
        npv = a4 / csv[4]; o = prot[4 * DIM + d]; prot[4 * DIM + d] = 0.4 * o + 0.6 * npv;
      }
      __syncthreads();
    }
  }
}

extern "C" void kernel_launch(void* const* d_in, const int* in_sizes, int n_in,
                              void* d_out, int out_size, void* d_ws, size_t ws_size,
                              hipStream_t stream) {
  const float* xs = (const float*)d_in[0];
  const float* xq = (const float*)d_in[1];
  const int*   ys = (const int*)d_in[2];
  const int*   yq = (const int*)d_in[3];
  float* out = (float*)d_out;
  char* ws   = (char*)d_ws;

  hipMemsetAsync(d_ws, 0, CTRL_BYTES, stream);

  size_t need_dbl = CTRL_BYTES + (size_t)B_RUNS * ep_bytes(sizeof(double));
  if (ws_size >= need_dbl) {
    hipLaunchKernelGGL(k1_hops<double>, dim3(B_RUNS), dim3(256), 0, stream, xs, xq, ws);
    hipLaunchKernelGGL(k2_epochs<double>, dim3(NBLK), dim3(256), 0, stream, ys, yq, ws, out);
  } else {
    hipLaunchKernelGGL(k1_hops<float>, dim3(B_RUNS), dim3(256), 0, stream, xs, xq, ws);
    hipLaunchKernelGGL(k2_epochs<float>, dim3(NBLK), dim3(256), 0, stream, ys, yq, ws, out);
  }
}

// Round 3
// 11852.543 us; speedup vs baseline: 1.4702x; 1.4702x over previous
//
#include <hip/hip_runtime.h>

// ---------------- problem constants ----------------
#define B_RUNS 500
#define WAYS   5
#define NSUP   25
#define NQ     75
#define NN     100
#define DIM    640
#define TOPK   6
#define KHOP   4
#define NEPOCH 10
#define MAXIT  1000

#define CTRL_BYTES  131072          // 32768 per-iteration barrier words
#define EPB  4                      // episodes per k2 block
#define NB2  (B_RUNS / EPB)         // 125 blocks -> guaranteed co-resident

// per-episode layout: feat [NN*DIM] f64 | Inv [NN*NN] f64 | prot [5*DIM] f64 | nrm [NN] f64
__host__ __device__ constexpr size_t ep_bytes() {
  size_t v = (size_t)(NN * DIM + NN * NN + WAYS * DIM + NN) * 8;
  return ((v + 255) / 256) * 256;
}

#define DYN_LDS_DBL (10000 + 1616)            // A (100x100) + ST (16x101)
#define DYN_LDS_BYTES (DYN_LDS_DBL * 8)       // 92928 B

__device__ __forceinline__ double wsum64d(double v) {
  #pragma unroll
  for (int off = 32; off > 0; off >>= 1) v += __shfl_xor(v, off, 64);
  return v;
}

// =====================================================================
// Kernel 1 (LDS version): per-episode hops + build_graph^2 + inverse
// A (100x100 fp64) lives entirely in dynamic LDS.
// =====================================================================
__global__ __launch_bounds__(256) void k1_lds(const float* __restrict__ xs,
                                              const float* __restrict__ xq,
                                              char* __restrict__ wsb) {
  extern __shared__ double dynb[];
  double* A  = dynb;           // 100x100
  double* ST = dynb + 10000;   // staging: 16x101 (gram) / 100x16 (G@feat)

  const int b = blockIdx.x;
  char* epb = wsb + CTRL_BYTES + (size_t)b * ep_bytes();
  double* feat = (double*)epb;                       // [100][640]
  double* Inv  = feat + NN * DIM;                    // [100][100]
  double* prot = Inv + NN * NN;                      // [5][640]
  double* nrm  = prot + WAYS * DIM;                  // [100]

  __shared__ double nsh[NN], Dsh[NN], rowk[NN], colk[NN];

  const int t  = threadIdx.x;
  const int tx = t & 15, ty = t >> 4;
  int ia[7], ja[7];
  #pragma unroll
  for (int a = 0; a < 7; ++a) { int v = ty + 16 * a; ia[a] = v < NN ? v : NN - 1; }
  #pragma unroll
  for (int a = 0; a < 7; ++a) { int v = tx + 16 * a; ja[a] = v < NN ? v : NN - 1; }

  const float* xsb = xs + (size_t)b * NSUP * DIM;
  const float* xqb = xq + (size_t)b * NQ * DIM;
  for (int e = t; e < NSUP * DIM; e += 256) feat[e] = (double)xsb[e];
  for (int e = t; e < NQ * DIM; e += 256)  feat[NSUP * DIM + e] = (double)xqb[e];
  __syncthreads();

  for (int hop = 0; hop < KHOP; ++hop) {
    // ---- C = F F^T (7x7 register tiles, 16-wide k chunks staged in ST) ----
    double acc[7][7];
    #pragma unroll
    for (int a = 0; a < 7; ++a)
      #pragma unroll
      for (int c = 0; c < 7; ++c) acc[a][c] = 0.0;
    for (int k0 = 0; k0 < DIM; k0 += 16) {
      for (int e = t; e < NN * 16; e += 256) {
        int r = e >> 4, kk = e & 15;
        ST[kk * 101 + r] = feat[r * DIM + k0 + kk];
      }
      __syncthreads();
      #pragma unroll 2
      for (int kk = 0; kk < 16; ++kk) {
        double rv[7], cv[7];
        #pragma unroll
        for (int a = 0; a < 7; ++a) rv[a] = ST[kk * 101 + ia[a]];
        #pragma unroll
        for (int c = 0; c < 7; ++c) cv[c] = ST[kk * 101 + ja[c]];
        #pragma unroll
        for (int a = 0; a < 7; ++a)
          #pragma unroll
          for (int c = 0; c < 7; ++c) acc[a][c] = fma(rv[a], cv[c], acc[a][c]);
      }
      __syncthreads();
    }
    #pragma unroll
    for (int a = 0; a < 7; ++a)
      #pragma unroll
      for (int c = 0; c < 7; ++c) {
        int i = ty + 16 * a, j = tx + 16 * c;
        if (i < NN && j < NN) A[i * NN + j] = acc[a][c];
      }
    __syncthreads();
    if (t < NN) nsh[t] = A[t * NN + t];
    __syncthreads();
    // A = exp(-10 * max(ni+nj-2c, 0))
    for (int e = t; e < NN * NN; e += 256) {
      int i = e / NN, j = e % NN;
      double d = (nsh[i] + nsh[j]) - 2.0 * A[e];
      d = d > 0.0 ? d : 0.0;
      A[e] = exp(-10.0 * d);
    }
    __syncthreads();
    // ---- top-6 per row (ties -> lowest index) ----
    if (t < NN) {
      unsigned long long m0 = 0ull, m1 = 0ull;
      for (int s = 0; s < TOPK; ++s) {
        double best = -1.0; int bj = 0;
        for (int j = 0; j < NN; ++j) {
          unsigned long long bit = (j < 64) ? ((m0 >> j) & 1ull) : ((m1 >> (j - 64)) & 1ull);
          if (bit) continue;
          double v = A[t * NN + j];
          if (v > best) { best = v; bj = j; }
        }
        if (bj < 64) m0 |= 1ull << bj; else m1 |= 1ull << (bj - 64);
      }
      for (int j = 0; j < NN; ++j) {
        unsigned long long bit = (j < 64) ? ((m0 >> j) & 1ull) : ((m1 >> (j - 64)) & 1ull);
        if (!bit) A[t * NN + j] = 0.0;
      }
    }
    __syncthreads();
    if (t < NN) {
      double s = 0.0;
      for (int j = 0; j < NN; ++j) s += A[t * NN + j];
      Dsh[t] = 1.0 / sqrt(s);
    }
    __syncthreads();
    // L = 0.5 I + 0.5 * (D_j * A * D_i)
    for (int e = t; e < NN * NN; e += 256) {
      int i = e / NN, j = e % NN;
      double w = (Dsh[j] * A[e]) * Dsh[i];
      A[e] = ((i == j) ? 0.5 : 0.0) + 0.5 * w;
    }
    __syncthreads();
    // ---- G = L @ L (registers), then overwrite A ----
    double gg[7][7];
    #pragma unroll
    for (int a = 0; a < 7; ++a)
      #pragma unroll
      for (int c = 0; c < 7; ++c) gg[a][c] = 0.0;
    for (int k = 0; k < NN; ++k) {
      double rv[7], cv[7];
      #pragma unroll
      for (int a = 0; a < 7; ++a) rv[a] = A[ia[a] * NN + k];
      #pragma unroll
      for (int c = 0; c < 7; ++c) cv[c] = A[k * NN + ja[c]];
      #pragma unroll
      for (int a = 0; a < 7; ++a)
        #pragma unroll
        for (int c = 0; c < 7; ++c) gg[a][c] = fma(rv[a], cv[c], gg[a][c]);
    }
    __syncthreads();   // all reads of L complete before overwrite
    #pragma unroll
    for (int a = 0; a < 7; ++a)
      #pragma unroll
      for (int c = 0; c < 7; ++c) {
        int i = ty + 16 * a, j = tx + 16 * c;
        if (i < NN && j < NN) A[i * NN + j] = gg[a][c];
      }
    __syncthreads();
    // ---- feat = G @ feat (16-col blocks; G read from LDS A) ----
    for (int c0 = 0; c0 < DIM; c0 += 16) {
      for (int e = t; e < NN * 16; e += 256) {
        int k = e >> 4, cc = e & 15;
        ST[k * 16 + cc] = feat[k * DIM + c0 + cc];
      }
      __syncthreads();
      double f[7];
      #pragma unroll
      for (int a = 0; a < 7; ++a) f[a] = 0.0;
      for (int k = 0; k < NN; ++k) {
        double fv = ST[k * 16 + tx];
        #pragma unroll
        for (int a = 0; a < 7; ++a) f[a] = fma(A[ia[a] * NN + k], fv, f[a]);
      }
      #pragma unroll
      for (int a = 0; a < 7; ++a) {
        int i = ty + 16 * a;
        if (i < NN) feat[i * DIM + c0 + tx] = f[a];
      }
      __syncthreads();
    }

    if (hop == KHOP - 1) {
      // ---- W = build_graph(build_graph(G)) in place ----
      for (int rep = 0; rep < 2; ++rep) {
        if (t < NN) A[t * NN + t] = 0.0;
        __syncthreads();
        if (t < NN) {
          double s = 0.0;
          for (int j = 0; j < NN; ++j) s += A[t * NN + j];
          Dsh[t] = 1.0 / sqrt(s);
        }
        __syncthreads();
        for (int e = t; e < NN * NN; e += 256) {
          int i = e / NN, j = e % NN;
          A[e] = (Dsh[j] * A[e]) * Dsh[i];
        }
        __syncthreads();
      }
      // M = I - 0.7*W
      for (int e = t; e < NN * NN; e += 256) {
        int i = e / NN, j = e % NN;
        A[e] = ((i == j) ? 1.0 : 0.0) - 0.7 * A[e];
      }
      __syncthreads();
      // ---- in-place Gauss-Jordan (sweep) inverse in LDS ----
      for (int k = 0; k < NN; ++k) {
        if (t < NN) { rowk[t] = A[k * NN + t]; colk[t] = A[t * NN + k]; }
        __syncthreads();
        double pinv = 1.0 / rowk[k];
        for (int e = t; e < NN * NN; e += 256) {
          int i = e / NN, j = e % NN;
          double v;
          if (i == k)      v = (j == k) ? pinv : rowk[j] * pinv;
          else if (j == k) v = -(colk[i] * pinv);
          else             v = A[e] - colk[i] * (rowk[j] * pinv);
          A[e] = v;
        }
        __syncthreads();
      }
      for (int e = t; e < NN * NN; e += 256) Inv[e] = A[e];
      // proto0 = mean over shots
      for (int e = t; e < WAYS * DIM; e += 256) {
        int w = e / DIM, d = e % DIM;
        double s = 0.0;
        #pragma unroll
        for (int sh = 0; sh < 5; ++sh) s += feat[(w * 5 + sh) * DIM + d];
        prot[e] = s / 5.0;
      }
      // feature norms
      if (t < NN) {
        double s = 0.0;
        for (int k = 0; k < DIM; ++k) {
          double f = feat[t * DIM + k];
          s = fma(f, f, s);
        }
        nrm[t] = s;
      }
    }
  }
}

// =====================================================================
// Kernel 1 fallback (global-memory A) — Round-2 verified version.
// Used only if >64KB dynamic LDS opt-in fails.
// =====================================================================
__global__ __launch_bounds__(256) void k1_glob(const float* __restrict__ xs,
                                               const float* __restrict__ xq,
                                               char* __restrict__ wsb) {
  const int b = blockIdx.x;
  char* epb = wsb + CTRL_BYTES + (size_t)b * ep_bytes();
  double* feat = (double*)epb;
  double* A    = feat + NN * DIM;
  double* prot = A + NN * NN;
  double* nrm  = prot + WAYS * DIM;

  __shared__ double SH[6600];
  __shared__ double nsh[NN], Dsh[NN], rowk[NN], colk[NN];

  const int t  = threadIdx.x;
  const int tx = t & 15, ty = t >> 4;
  int ia[7], ja[7];
  #pragma unroll
  for (int a = 0; a < 7; ++a) { int v = ty + 16 * a; ia[a] = v < NN ? v : NN - 1; }
  #pragma unroll
  for (int a = 0; a < 7; ++a) { int v = tx + 16 * a; ja[a] = v < NN ? v : NN - 1; }

  const float* xsb = xs + (size_t)b * NSUP * DIM;
  const float* xqb = xq + (size_t)b * NQ * DIM;
  for (int e = t; e < NSUP * DIM; e += 256) feat[e] = (double)xsb[e];
  for (int e = t; e < NQ * DIM; e += 256)  feat[NSUP * DIM + e] = (double)xqb[e];
  __syncthreads();

  for (int hop = 0; hop < KHOP; ++hop) {
    double acc[7][7];
    #pragma unroll
    for (int a = 0; a < 7; ++a)
      #pragma unroll
      for (int c = 0; c < 7; ++c) acc[a][c] = 0.0;
    for (int k0 = 0; k0 < DIM; k0 += 16) {
      for (int e = t; e < NN * 16; e += 256) {
        int r = e >> 4, kk = e & 15;
        SH[kk * NN + r] = feat[r * DIM + k0 + kk];
      }
      __syncthreads();
      #pragma unroll 2
      for (int kk = 0; kk < 16; ++kk) {
        double rv[7], cv[7];
        #pragma unroll
        for (int a = 0; a < 7; ++a) rv[a] = SH[kk * NN + ia[a]];
        #pragma unroll
        for (int c = 0; c < 7; ++c) cv[c] = SH[kk * NN + ja[c]];
        #pragma unroll
        for (int a = 0; a < 7; ++a)
          #pragma unroll
          for (int c = 0; c < 7; ++c) acc[a][c] = fma(rv[a], cv[c], acc[a][c]);
      }
      __syncthreads();
    }
    #pragma unroll
    for (int a = 0; a < 7; ++a)
      #pragma unroll
      for (int c = 0; c < 7; ++c) {
        int i = ty + 16 * a, j = tx + 16 * c;
        if (i < NN && j < NN) A[i * NN + j] = acc[a][c];
      }
    __syncthreads();
    if (t < NN) nsh[t] = A[t * NN + t];
    __syncthreads();
    for (int e = t; e < NN * NN; e += 256) {
      int i = e / NN, j = e % NN;
      double d = (nsh[i] + nsh[j]) - 2.0 * A[e];
      d = d > 0.0 ? d : 0.0;
      A[e] = exp(-10.0 * d);
    }
    __syncthreads();
    if (t < NN) {
      unsigned long long m0 = 0ull, m1 = 0ull;
      for (int s = 0; s < TOPK; ++s) {
        double best = -1.0; int bj = 0;
        for (int j = 0; j < NN; ++j) {
          unsigned long long bit = (j < 64) ? ((m0 >> j) & 1ull) : ((m1 >> (j - 64)) & 1ull);
          if (bit) continue;
          double v = A[t * NN + j];
          if (v > best) { best = v; bj = j; }
        }
        if (bj < 64) m0 |= 1ull << bj; else m1 |= 1ull << (bj - 64);
      }
      for (int j = 0; j < NN; ++j) {
        unsigned long long bit = (j < 64) ? ((m0 >> j) & 1ull) : ((m1 >> (j - 64)) & 1ull);
        if (!bit) A[t * NN + j] = 0.0;
      }
    }
    __syncthreads();
    if (t < NN) {
      double s = 0.0;
      for (int j = 0; j < NN; ++j) s += A[t * NN + j];
      Dsh[t] = 1.0 / sqrt(s);
    }
    __syncthreads();
    for (int e = t; e < NN * NN; e += 256) {
      int i = e / NN, j = e % NN;
      double w = (Dsh[j] * A[e]) * Dsh[i];
      A[e] = ((i == j) ? 0.5 : 0.0) + 0.5 * w;
    }
    __syncthreads();
    double gg[7][7];
    #pragma unroll
    for (int a = 0; a < 7; ++a)
      #pragma unroll
      for (int c = 0; c < 7; ++c) gg[a][c] = 0.0;
    for (int k = 0; k < NN; ++k) {
      double rv[7], cv[7];
      #pragma unroll
      for (int a = 0; a < 7; ++a) rv[a] = A[ia[a] * NN + k];
      #pragma unroll
      for (int c = 0; c < 7; ++c) cv[c] = A[k * NN + ja[c]];
      #pragma unroll
      for (int a = 0; a < 7; ++a)
        #pragma unroll
        for (int c = 0; c < 7; ++c) gg[a][c] = fma(rv[a], cv[c], gg[a][c]);
    }
    __syncthreads();
    #pragma unroll
    for (int a = 0; a < 7; ++a)
      #pragma unroll
      for (int c = 0; c < 7; ++c) {
        int i = ty + 16 * a, j = tx + 16 * c;
        if (i < NN && j < NN) A[i * NN + j] = gg[a][c];
      }
    __syncthreads();
    double* Fb = SH;
    double* Gb = SH + 1600;
    for (int c0 = 0; c0 < DIM; c0 += 16) {
      for (int e = t; e < NN * 16; e += 256) {
        int k = e >> 4, cc = e & 15;
        Fb[e] = feat[k * DIM + c0 + cc];
      }
      double f[7];
      #pragma unroll
      for (int a = 0; a < 7; ++a) f[a] = 0.0;
      for (int kh = 0; kh < 2; ++kh) {
        for (int e = t; e < NN * 50; e += 256) {
          int i = e / 50, kk = e % 50;
          Gb[e] = A[i * NN + kh * 50 + kk];
        }
        __syncthreads();
        for (int kk = 0; kk < 50; ++kk) {
          double fv = Fb[(kh * 50 + kk) * 16 + tx];
          #pragma unroll
          for (int a = 0; a < 7; ++a) f[a] = fma(Gb[ia[a] * 50 + kk], fv, f[a]);
        }
        __syncthreads();
      }
      #pragma unroll
      for (int a = 0; a < 7; ++a) {
        int i = ty + 16 * a;
        if (i < NN) feat[i * DIM + c0 + tx] = f[a];
      }
      __syncthreads();
    }

    if (hop == KHOP - 1) {
      for (int rep = 0; rep < 2; ++rep) {
        if (t < NN) A[t * NN + t] = 0.0;
        __syncthreads();
        if (t < NN) {
          double s = 0.0;
          for (int j = 0; j < NN; ++j) s += A[t * NN + j];
          Dsh[t] = 1.0 / sqrt(s);
        }
        __syncthreads();
        for (int e = t; e < NN * NN; e += 256) {
          int i = e / NN, j = e % NN;
          A[e] = (Dsh[j] * A[e]) * Dsh[i];
        }
        __syncthreads();
      }
      for (int e = t; e < NN * NN; e += 256) {
        int i = e / NN, j = e % NN;
        A[e] = ((i == j) ? 1.0 : 0.0) - 0.7 * A[e];
      }
      __syncthreads();
      for (int k = 0; k < NN; ++k) {
        if (t < NN) { rowk[t] = A[k * NN + t]; colk[t] = A[t * NN + k]; }
        __syncthreads();
        double pinv = 1.0 / rowk[k];
        for (int e = t; e < NN * NN; e += 256) {
          int i = e / NN, j = e % NN;
          double v;
          if (i == k)      v = (j == k) ? pinv : rowk[j] * pinv;
          else if (j == k) v = -(colk[i] * pinv);
          else             v = A[e] - colk[i] * (rowk[j] * pinv);
          A[e] = v;
        }
        __syncthreads();
      }
      for (int e = t; e < WAYS * DIM; e += 256) {
        int w = e / DIM, d = e % DIM;
        double s = 0.0;
        #pragma unroll
        for (int sh = 0; sh < 5; ++sh) s += feat[(w * 5 + sh) * DIM + d];
        prot[e] = s / 5.0;
      }
      if (t < NN) {
        double s = 0.0;
        for (int k = 0; k < DIM; ++k) {
          double f = feat[t * DIM + k];
          s = fma(f, f, s);
        }
        nrm[t] = s;
      }
    }
  }
}

// =====================================================================
// Kernel 2: 4 episodes per block, 125 blocks; one device atomic per
// block per Sinkhorn iteration (count*256 + flag packed in one word).
// =====================================================================
__global__ __launch_bounds__(256) void k2_epochs(const int* __restrict__ ys,
                                                 const int* __restrict__ yq,
                                                 char* __restrict__ wsb,
                                                 float* __restrict__ out) {
  const int b = blockIdx.x;
  const double* featA[EPB]; const double* InvA[EPB]; double* protA[EPB]; const double* nrmA[EPB];
  #pragma unroll
  for (int q = 0; q < EPB; ++q) {
    char* epb = wsb + CTRL_BYTES + (size_t)(b * EPB + q) * ep_bytes();
    double* f = (double*)epb;
    featA[q] = f;
    InvA[q]  = f + NN * DIM;
    protA[q] = f + NN * DIM + NN * NN;
    nrmA[q]  = f + NN * DIM + NN * NN + WAYS * DIM;
  }
  unsigned* wordc = (unsigned*)wsb;   // per-iteration barrier words (zeroed)

  __shared__ double Z[EPB][NN * WAYS];     // 16000 B
  __shared__ double UPA[EPB][NN];          // 3200
  __shared__ double UAA[EPB][NN];          // 3200
  __shared__ double csv[EPB][WAYS];
  __shared__ double buf[WAYS * DIM];       // protS / Zn overlay (25600 B)
  __shared__ double pn[WAYS];
  __shared__ int ysS[EPB][NSUP];
  __shared__ unsigned long long redd[EPB];
  __shared__ int rediA[EPB];
  __shared__ unsigned flagsh;

  const int t  = threadIdx.x;
  const int wv = t >> 6, ln = t & 63;
  unsigned git = 0;   // global sinkhorn iteration index (uniform across blocks)

  for (int e = t; e < EPB * NSUP; e += 256)
    ysS[e / NSUP][e % NSUP] = ys[(b * EPB + e / NSUP) * NSUP + e % NSUP];
  __syncthreads();

  auto sinkhorn = [&](int base, int n, double cval, bool clamp) {
    for (int e = t; e < EPB * n; e += 256) UPA[e / n][e % n] = 0.0;
    int it = 1;
    for (;;) {
      __syncthreads();
      if (t < EPB) redd[t] = 0ull;
      __syncthreads();
      for (int e = t; e < EPB * n; e += 256) {
        int q = e / n, r = e % n;
        double u = 0.0;
        #pragma unroll
        for (int w = 0; w < WAYS; ++w) u += Z[q][(base + r) * WAYS + w];
        UAA[q][r] = u;
        double d = fabs(UPA[q][r] - u);
        atomicMax(&redd[q], (unsigned long long)__double_as_longlong(d));
      }
      __syncthreads();
      if (t == 0) {
        unsigned lf = 0;
        #pragma unroll
        for (int q = 0; q < EPB; ++q)
          if (__longlong_as_double((long long)redd[q]) > 1e-3) lf = 1u;
        unsigned idx = (git < 32000u) ? git : 31999u;
        __hip_atomic_fetch_add(&wordc[idx], 256u + lf, __ATOMIC_ACQ_REL, __HIP_MEMORY_SCOPE_AGENT);
        unsigned v; long sp = 0;
        for (;;) {
          v = __hip_atomic_load(&wordc[idx], __ATOMIC_RELAXED, __HIP_MEMORY_SCOPE_AGENT);
          if (v >= (unsigned)NB2 * 256u) break;
          __builtin_amdgcn_s_sleep(8);
          if (++sp > 2000000L) break;   // ~0.3s sticky timeout: terminate, don't hang
        }
        flagsh = ((v & 255u) != 0u) ? 1u : 0u;
      }
      __syncthreads();
      unsigned go = flagsh;
      ++git;
      if (!(go != 0u && it <= MAXIT)) break;
      // body: row normalize, column balance, clamp labeled
      for (int e = t; e < EPB * n; e += 256) {
        int q = e / n, r = e % n;
        double inv = 1.0 / UAA[q][r];
        #pragma unroll
        for (int w = 0; w < WAYS; ++w) Z[q][(base + r) * WAYS + w] *= inv;
        UPA[q][r] = UAA[q][r];
      }
      __syncthreads();
      if (t < EPB * WAYS) {
        int q = t / WAYS, w = t % WAYS;
        double s = 0.0;
        for (int r = 0; r < n; ++r) s += Z[q][(base + r) * WAYS + w];
        csv[q][w] = cval / s;
      }
      __syncthreads();
      for (int e = t; e < EPB * n; e += 256) {
        int q = e / n, r = e % n;
        #pragma unroll
        for (int w = 0; w < WAYS; ++w) Z[q][(base + r) * WAYS + w] *= csv[q][w];
      }
      if (clamp) {
        __syncthreads();
        for (int e = t; e < EPB * NSUP; e += 256) {
          int q = e / NSUP, i = e % NSUP;
          #pragma unroll
          for (int w = 0; w < WAYS; ++w) Z[q][i * WAYS + w] = (ysS[q][i] == w) ? 1.0 : 0.0;
        }
      }
      ++it;
    }
    __syncthreads();
  };

  for (int epi = 0; epi <= NEPOCH; ++epi) {
    // ---- Pq for each episode (sequential; protS in shared buf) ----
    for (int q = 0; q < EPB; ++q) {
      for (int e = t; e < WAYS * DIM; e += 256) buf[e] = protA[q][e];
      __syncthreads();
      if (t < WAYS) {
        double s = 0.0;
        for (int k = 0; k < DIM; ++k) { double p = buf[t * DIM + k]; s = fma(p, p, s); }
        pn[t] = s;
      }
      __syncthreads();
      for (int r = NSUP + wv; r < NN; r += 4) {
        double a0 = 0, a1 = 0, a2 = 0, a3 = 0, a4 = 0;
        #pragma unroll
        for (int m = 0; m < DIM / 64; ++m) {
          int k = ln + 64 * m;
          double f = featA[q][r * DIM + k];
          a0 = fma(f, buf[0 * DIM + k], a0);
          a1 = fma(f, buf[1 * DIM + k], a1);
          a2 = fma(f, buf[2 * DIM + k], a2);
          a3 = fma(f, buf[3 * DIM + k], a3);
          a4 = fma(f, buf[4 * DIM + k], a4);
        }
        a0 = wsum64d(a0); a1 = wsum64d(a1); a2 = wsum64d(a2);
        a3 = wsum64d(a3); a4 = wsum64d(a4);
        if (ln == 0) {
          double nr = nrmA[q][r];
          double d0 = (nr + pn[0]) - 2.0 * a0;
          double d1 = (nr + pn[1]) - 2.0 * a1;
          double d2 = (nr + pn[2]) - 2.0 * a2;
          double d3 = (nr + pn[3]) - 2.0 * a3;
          double d4 = (nr + pn[4]) - 2.0 * a4;
          Z[q][r * WAYS + 0] = exp(-10.0 * (d0 > 0.0 ? d0 : 0.0));
          Z[q][r * WAYS + 1] = exp(-10.0 * (d1 > 0.0 ? d1 : 0.0));
          Z[q][r * WAYS + 2] = exp(-10.0 * (d2 > 0.0 ? d2 : 0.0));
          Z[q][r * WAYS + 3] = exp(-10.0 * (d3 > 0.0 ? d3 : 0.0));
          Z[q][r * WAYS + 4] = exp(-10.0 * (d4 > 0.0 ? d4 : 0.0));
        }
      }
      __syncthreads();
    }
    sinkhorn(NSUP, NQ, 15.0, false);

    if (epi == NEPOCH) {
      if (t < EPB) rediA[t] = 0;
      __syncthreads();
      for (int e = t; e < EPB * NQ; e += 256) {
        int q = e / NQ, i = e % NQ;
        int row = NSUP + i;
        double bv = Z[q][row * WAYS + 0]; int am = 0;
        #pragma unroll
        for (int w = 1; w < WAYS; ++w) {
          double v = Z[q][row * WAYS + w];
          if (v > bv) { bv = v; am = w; }
        }
        if (am == yq[(b * EPB + q) * NQ + i]) atomicAdd(&rediA[q], 1);
      }
      __syncthreads();
      if (t < EPB) out[b * EPB + t] = (float)((double)rediA[t] / 75.0);
    } else {
      // concat one-hot support rows
      for (int e = t; e < EPB * NSUP; e += 256) {
        int q = e / NSUP, i = e % NSUP;
        #pragma unroll
        for (int w = 0; w < WAYS; ++w) Z[q][i * WAYS + w] = (ysS[q][i] == w) ? 1.0 : 0.0;
      }
      __syncthreads();
      // Zn = Inv @ Z : wave wv handles episode wv (EPB == 4 waves)
      {
        int q = wv;
        for (int r = 0; r < NN; ++r) {
          double a0 = 0, a1 = 0, a2 = 0, a3 = 0, a4 = 0;
          for (int k = ln; k < NN; k += 64) {
            double iv = InvA[q][r * NN + k];
            a0 = fma(iv, Z[q][k * WAYS + 0], a0);
            a1 = fma(iv, Z[q][k * WAYS + 1], a1);
            a2 = fma(iv, Z[q][k * WAYS + 2], a2);
            a3 = fma(iv, Z[q][k * WAYS + 3], a3);
            a4 = fma(iv, Z[q][k * WAYS + 4], a4);
          }
          a0 = wsum64d(a0); a1 = wsum64d(a1); a2 = wsum64d(a2);
          a3 = wsum64d(a3); a4 = wsum64d(a4);
          if (ln == 0) {
            buf[q * (NN * WAYS) + r * WAYS + 0] = a0;
            buf[q * (NN * WAYS) + r * WAYS + 1] = a1;
            buf[q * (NN * WAYS) + r * WAYS + 2] = a2;
            buf[q * (NN * WAYS) + r * WAYS + 3] = a3;
            buf[q * (NN * WAYS) + r * WAYS + 4] = a4;
          }
        }
      }
      __syncthreads();
      for (int e = t; e < EPB * NN * WAYS; e += 256)
        Z[e / (NN * WAYS)][e % (NN * WAYS)] = buf[e];
      __syncthreads();
      sinkhorn(0, NN, 20.0, true);
      // column sums of final Z
      if (t < EPB * WAYS) {
        int q = t / WAYS, w = t % WAYS;
        double s = 0.0;
        for (int r = 0; r < NN; ++r) s += Z[q][r * WAYS + w];
        csv[q][w] = s;
      }
      __syncthreads();
      // proto = 0.4*proto + 0.6*(Z^T feat / colsum), per episode
      for (int q = 0; q < EPB; ++q) {
        for (int d = t; d < DIM; d += 256) {
          double a0 = 0, a1 = 0, a2 = 0, a3 = 0, a4 = 0;
          for (int n = 0; n < NN; ++n) {
            double f = featA[q][n * DIM + d];
            a0 = fma(Z[q][n * WAYS + 0], f, a0);
            a1 = fma(Z[q][n * WAYS + 1], f, a1);
            a2 = fma(Z[q][n * WAYS + 2], f, a2);
            a3 = fma(Z[q][n * WAYS + 3], f, a3);
            a4 = fma(Z[q][n * WAYS + 4], f, a4);
          }
          double o, npv;
          npv = a0 / csv[q][0]; o = protA[q][0 * DIM + d]; protA[q][0 * DIM + d] = 0.4 * o + 0.6 * npv;
          npv = a1 / csv[q][1]; o = protA[q][1 * DIM + d]; protA[q][1 * DIM + d] = 0.4 * o + 0.6 * npv;
          npv = a2 / csv[q][2]; o = protA[q][2 * DIM + d]; protA[q][2 * DIM + d] = 0.4 * o + 0.6 * npv;
          npv = a3 / csv[q][3]; o = protA[q][3 * DIM + d]; protA[q][3 * DIM + d] = 0.4 * o + 0.6 * npv;
          npv = a4 / csv[q][4]; o = protA[q][4 * DIM + d]; protA[q][4 * DIM + d] = 0.4 * o + 0.6 * npv;
        }
      }
      __syncthreads();
    }
  }
}

extern "C" void kernel_launch(void* const* d_in, const int* in_sizes, int n_in,
                              void* d_out, int out_size, void* d_ws, size_t ws_size,
                              hipStream_t stream) {
  const float* xs = (const float*)d_in[0];
  const float* xq = (const float*)d_in[1];
  const int*   ys = (const int*)d_in[2];
  const int*   yq = (const int*)d_in[3];
  float* out = (float*)d_out;
  char* ws   = (char*)d_ws;

  hipMemsetAsync(d_ws, 0, CTRL_BYTES, stream);

  // opt in to >64KB dynamic LDS (idempotent; same result every call)
  hipError_t e = hipFuncSetAttribute((const void*)k1_lds,
                                     hipFuncAttributeMaxDynamicSharedMemorySize,
                                     DYN_LDS_BYTES);
  if (e == hipSuccess) {
    hipLaunchKernelGGL(k1_lds, dim3(B_RUNS), dim3(256), DYN_LDS_BYTES, stream, xs, xq, ws);
  } else {
    hipLaunchKernelGGL(k1_glob, dim3(B_RUNS), dim3(256), 0, stream, xs, xq, ws);
  }
  hipLaunchKernelGGL(k2_epochs, dim3(NB2), dim3(256), 0, stream, ys, yq, ws, out);
}

// Round 4
// 8043.674 us; speedup vs baseline: 2.1663x; 1.4735x over previous
//
#include <hip/hip_runtime.h>

// ---------------- problem constants ----------------
#define B_RUNS 500
#define WAYS   5
#define NSUP   25
#define NQ     75
#define NN     100
#define DIM    640
#define TOPK   6
#define KHOP   4
#define NEPOCH 10

#define CTRL_BYTES  131072
#define EPB  2                      // episodes per k2 block
#define NB2  (B_RUNS / EPB)         // 250 blocks <= 256 CUs -> co-resident

// per-episode layout: feat [NN*DIM] | Inv [NN*NN] | prot [5*DIM] | nrm [NN], all f64
__host__ __device__ constexpr size_t ep_bytes() {
  size_t v = (size_t)(NN * DIM + NN * NN + WAYS * DIM + NN) * 8;
  return ((v + 255) / 256) * 256;
}

#define DYN_LDS_DBL (10000 + 2 * 1616)        // A (100x100) + per-team staging
#define DYN_LDS_BYTES (DYN_LDS_DBL * 8)       // 105856 B

__device__ __forceinline__ double wsum64d(double v) {
  #pragma unroll
  for (int off = 32; off > 0; off >>= 1) v += __shfl_xor(v, off, 64);
  return v;
}
__device__ __forceinline__ double wmax64d(double v) {
  #pragma unroll
  for (int off = 32; off > 0; off >>= 1) v = fmax(v, __shfl_xor(v, off, 64));
  return v;
}

// =====================================================================
// Kernel 1: 512 threads, two 256-thread teams; A (100x100 f64) in LDS.
// =====================================================================
__global__ __launch_bounds__(512) void k1_lds(const float* __restrict__ xs,
                                              const float* __restrict__ xq,
                                              char* __restrict__ wsb) {
  extern __shared__ double dynb[];
  double* A  = dynb;            // 100x100
  double* ST = dynb + 10000;    // 2 teams x 1616 staging

  const int b = blockIdx.x;
  char* epb = wsb + CTRL_BYTES + (size_t)b * ep_bytes();
  double* feat = (double*)epb;
  double* Inv  = feat + NN * DIM;
  double* prot = Inv + NN * NN;
  double* nrm  = prot + WAYS * DIM;

  __shared__ double nsh[NN], Dsh[NN], rowk[NN], colk[NN];

  const int t  = threadIdx.x;
  const int tm = t >> 8;              // team 0/1
  const int tt = t & 255;
  const int tx = tt & 15, ty = tt >> 4;
  double* STt = ST + tm * 1616;

  int ia[7], ja[7];
  #pragma unroll
  for (int a = 0; a < 7; ++a) { int v = ty + 16 * a; ia[a] = v < NN ? v : NN - 1; }
  #pragma unroll
  for (int a = 0; a < 7; ++a) { int v = tx + 16 * a; ja[a] = v < NN ? v : NN - 1; }
  // L^2 row-split tiles (team tm owns rows tm*50 .. tm*50+49)
  int ia2[4];
  #pragma unroll
  for (int a = 0; a < 4; ++a) { int rr = ty + 16 * a; ia2[a] = tm * 50 + (rr < 50 ? rr : 49); }

  const float* xsb = xs + (size_t)b * NSUP * DIM;
  const float* xqb = xq + (size_t)b * NQ * DIM;
  for (int e = t; e < NSUP * DIM; e += 512) feat[e] = (double)xsb[e];
  for (int e = t; e < NQ * DIM; e += 512)  feat[NSUP * DIM + e] = (double)xqb[e];
  __syncthreads();

  for (int hop = 0; hop < KHOP; ++hop) {
    // ---- C = F F^T, split-K across teams (team tm: chunks 2c+tm) ----
    double acc[7][7];
    #pragma unroll
    for (int a = 0; a < 7; ++a)
      #pragma unroll
      for (int c = 0; c < 7; ++c) acc[a][c] = 0.0;
    for (int chunk = 0; chunk < 20; ++chunk) {
      int k0 = (chunk * 2 + tm) * 16;
      for (int e = tt; e < NN * 16; e += 256) {
        int r = e >> 4, kk = e & 15;
        STt[kk * 101 + r] = feat[r * DIM + k0 + kk];
      }
      __syncthreads();
      #pragma unroll 2
      for (int kk = 0; kk < 16; ++kk) {
        double rv[7], cv[7];
        #pragma unroll
        for (int a = 0; a < 7; ++a) rv[a] = STt[kk * 101 + ia[a]];
        #pragma unroll
        for (int c = 0; c < 7; ++c) cv[c] = STt[kk * 101 + ja[c]];
        #pragma unroll
        for (int a = 0; a < 7; ++a)
          #pragma unroll
          for (int c = 0; c < 7; ++c) acc[a][c] = fma(rv[a], cv[c], acc[a][c]);
      }
      __syncthreads();
    }
    // combine team partials into A
    if (tm == 1) {
      #pragma unroll
      for (int a = 0; a < 7; ++a)
        #pragma unroll
        for (int c = 0; c < 7; ++c) {
          int i = ty + 16 * a, j = tx + 16 * c;
          if (i < NN && j < NN) A[i * NN + j] = acc[a][c];
        }
    }
    __syncthreads();
    if (tm == 0) {
      #pragma unroll
      for (int a = 0; a < 7; ++a)
        #pragma unroll
        for (int c = 0; c < 7; ++c) {
          int i = ty + 16 * a, j = tx + 16 * c;
          if (i < NN && j < NN) A[i * NN + j] = acc[a][c] + A[i * NN + j];
        }
    }
    __syncthreads();
    if (t < NN) nsh[t] = A[t * NN + t];
    __syncthreads();
    // A = exp(-10 * max(ni+nj-2c, 0))
    for (int e = t; e < NN * NN; e += 512) {
      int i = e / NN, j = e % NN;
      double d = (nsh[i] + nsh[j]) - 2.0 * A[e];
      d = d > 0.0 ? d : 0.0;
      A[e] = exp(-10.0 * d);
    }
    __syncthreads();
    // ---- top-6 per row (ties -> lowest index) ----
    if (t < NN) {
      unsigned long long m0 = 0ull, m1 = 0ull;
      for (int s = 0; s < TOPK; ++s) {
        double best = -1.0; int bj = 0;
        for (int j = 0; j < NN; ++j) {
          unsigned long long bit = (j < 64) ? ((m0 >> j) & 1ull) : ((m1 >> (j - 64)) & 1ull);
          if (bit) continue;
          double v = A[t * NN + j];
          if (v > best) { best = v; bj = j; }
        }
        if (bj < 64) m0 |= 1ull << bj; else m1 |= 1ull << (bj - 64);
      }
      for (int j = 0; j < NN; ++j) {
        unsigned long long bit = (j < 64) ? ((m0 >> j) & 1ull) : ((m1 >> (j - 64)) & 1ull);
        if (!bit) A[t * NN + j] = 0.0;
      }
    }
    __syncthreads();
    if (t < NN) {
      double s = 0.0;
      for (int j = 0; j < NN; ++j) s += A[t * NN + j];
      Dsh[t] = 1.0 / sqrt(s);
    }
    __syncthreads();
    // L = 0.5 I + 0.5 * (D_j * A * D_i)
    for (int e = t; e < NN * NN; e += 512) {
      int i = e / NN, j = e % NN;
      double w = (Dsh[j] * A[e]) * Dsh[i];
      A[e] = ((i == j) ? 0.5 : 0.0) + 0.5 * w;
    }
    __syncthreads();
    // ---- G = L @ L, row-split across teams (4x7 tiles, full K) ----
    {
      double gg[4][7];
      #pragma unroll
      for (int a = 0; a < 4; ++a)
        #pragma unroll
        for (int c = 0; c < 7; ++c) gg[a][c] = 0.0;
      for (int k = 0; k < NN; ++k) {
        double rv[4], cv[7];
        #pragma unroll
        for (int a = 0; a < 4; ++a) rv[a] = A[ia2[a] * NN + k];
        #pragma unroll
        for (int c = 0; c < 7; ++c) cv[c] = A[k * NN + ja[c]];
        #pragma unroll
        for (int a = 0; a < 4; ++a)
          #pragma unroll
          for (int c = 0; c < 7; ++c) gg[a][c] = fma(rv[a], cv[c], gg[a][c]);
      }
      __syncthreads();   // all reads of L complete before overwrite
      #pragma unroll
      for (int a = 0; a < 4; ++a)
        #pragma unroll
        for (int c = 0; c < 7; ++c) {
          int rr = ty + 16 * a, j = tx + 16 * c;
          if (rr < 50 && j < NN) A[(tm * 50 + rr) * NN + j] = gg[a][c];
        }
      __syncthreads();
    }
    // ---- feat = G @ feat, column-split across teams (16-col blocks) ----
    for (int blk = 0; blk < 20; ++blk) {
      int c0 = (blk * 2 + tm) * 16;
      for (int e = tt; e < NN * 16; e += 256) {
        int k = e >> 4, cc = e & 15;
        STt[k * 16 + cc] = feat[k * DIM + c0 + cc];
      }
      __syncthreads();
      double f[7];
      #pragma unroll
      for (int a = 0; a < 7; ++a) f[a] = 0.0;
      for (int k = 0; k < NN; ++k) {
        double fv = STt[k * 16 + tx];
        #pragma unroll
        for (int a = 0; a < 7; ++a) f[a] = fma(A[ia[a] * NN + k], fv, f[a]);
      }
      #pragma unroll
      for (int a = 0; a < 7; ++a) {
        int i = ty + 16 * a;
        if (i < NN) feat[i * DIM + c0 + tx] = f[a];
      }
      __syncthreads();
    }

    if (hop == KHOP - 1) {
      // ---- W = build_graph(build_graph(G)) in place ----
      for (int rep = 0; rep < 2; ++rep) {
        if (t < NN) A[t * NN + t] = 0.0;
        __syncthreads();
        if (t < NN) {
          double s = 0.0;
          for (int j = 0; j < NN; ++j) s += A[t * NN + j];
          Dsh[t] = 1.0 / sqrt(s);
        }
        __syncthreads();
        for (int e = t; e < NN * NN; e += 512) {
          int i = e / NN, j = e % NN;
          A[e] = (Dsh[j] * A[e]) * Dsh[i];
        }
        __syncthreads();
      }
      // M = I - 0.7*W
      for (int e = t; e < NN * NN; e += 512) {
        int i = e / NN, j = e % NN;
        A[e] = ((i == j) ? 1.0 : 0.0) - 0.7 * A[e];
      }
      __syncthreads();
      // ---- in-place Gauss-Jordan (sweep) inverse in LDS ----
      for (int k = 0; k < NN; ++k) {
        if (t < NN) { rowk[t] = A[k * NN + t]; colk[t] = A[t * NN + k]; }
        __syncthreads();
        double pinv = 1.0 / rowk[k];
        for (int e = t; e < NN * NN; e += 512) {
          int i = e / NN, j = e % NN;
          double v;
          if (i == k)      v = (j == k) ? pinv : rowk[j] * pinv;
          else if (j == k) v = -(colk[i] * pinv);
          else             v = A[e] - colk[i] * (rowk[j] * pinv);
          A[e] = v;
        }
        __syncthreads();
      }
      for (int e = t; e < NN * NN; e += 512) Inv[e] = A[e];
      // proto0 = mean over shots
      for (int e = t; e < WAYS * DIM; e += 512) {
        int w = e / DIM, d = e % DIM;
        double s = 0.0;
        #pragma unroll
        for (int sh = 0; sh < 5; ++sh) s += feat[(w * 5 + sh) * DIM + d];
        prot[e] = s / 5.0;
      }
      // feature norms
      if (t < NN) {
        double s = 0.0;
        for (int k = 0; k < DIM; ++k) {
          double f = feat[t * DIM + k];
          s = fma(f, f, s);
        }
        nrm[t] = s;
      }
    }
  }
}

// =====================================================================
// Kernel 2: 250 blocks x 2 episodes; in-register wave Sinkhorn with
// decoupled convergence (atomicMax target + ~2 grid barriers per call).
// =====================================================================
__global__ __launch_bounds__(256) void k2_epochs(const int* __restrict__ ys,
                                                 const int* __restrict__ yq,
                                                 char* __restrict__ wsb,
                                                 float* __restrict__ out) {
  const int b = blockIdx.x;
  const double* featA[EPB]; const double* InvA[EPB]; double* protA[EPB]; const double* nrmA[EPB];
  #pragma unroll
  for (int q = 0; q < EPB; ++q) {
    char* epb = wsb + CTRL_BYTES + (size_t)(b * EPB + q) * ep_bytes();
    double* f = (double*)epb;
    featA[q] = f;
    InvA[q]  = f + NN * DIM;
    protA[q] = f + NN * DIM + NN * NN;
    nrmA[q]  = f + NN * DIM + NN * NN + WAYS * DIM;
  }
  unsigned* arr  = (unsigned*)wsb;          // [4096] barrier arrivals per round
  unsigned* tmax = (unsigned*)wsb + 4096;   // [4096] atomicMax of body counts

  __shared__ double Z[EPB][NN * WAYS];      // 8000 B
  __shared__ double buf[WAYS * DIM];        // protS / Zn overlay (25600 B)
  __shared__ double pn[WAYS];
  __shared__ double csv[EPB][WAYS];
  __shared__ int ysS[EPB][NSUP];
  __shared__ unsigned mloc[EPB];
  __shared__ unsigned Tsh;
  __shared__ int rediA[EPB];

  const int t  = threadIdx.x;
  const int wv = t >> 6, ln = t & 63;
  unsigned rnd = 0;   // global barrier-round index (uniform across blocks)

  for (int e = t; e < EPB * NSUP; e += 256)
    ysS[e / NSUP][e % NSUP] = ys[(b * EPB + e / NSUP) * NSUP + e % NSUP];
  __syncthreads();

  // ---- decoupled Sinkhorn: episode q lives in wave q's registers ----
  auto sinkhorn = [&](int base, int n, double cval, bool clamp) {
    const int q = wv;
    const bool own = (q < EPB);
    const int r0 = ln, r1 = ln + 64;
    const bool h1 = (r1 < n);
    double p0[WAYS], p1[WAYS];
    double up0 = 0.0, up1 = 0.0, u0 = 0.0, u1 = 0.0, dcur = 0.0;
    int m = 0;
    int ysq = -1;
    if (own) {
      #pragma unroll
      for (int w = 0; w < WAYS; ++w) {
        p0[w] = Z[q][(base + r0) * WAYS + w];
        p1[w] = h1 ? Z[q][(base + r1) * WAYS + w] : 0.0;
      }
      if (clamp && r0 < NSUP) ysq = ysS[q][r0];
      u0 = p0[0] + p0[1] + p0[2] + p0[3] + p0[4];
      if (h1) u1 = p1[0] + p1[1] + p1[2] + p1[3] + p1[4];
      double dl = fabs(up0 - u0);
      if (h1) dl = fmax(dl, fabs(up1 - u1));
      dcur = wmax64d(dl);
    }
    unsigned target = 0;
    for (;;) {
      if (own) {
        while (m < 1000 && ((unsigned)m < target || dcur > 1e-3)) {
          // body: row normalize
          double i0 = 1.0 / u0;
          #pragma unroll
          for (int w = 0; w < WAYS; ++w) p0[w] *= i0;
          up0 = u0;
          if (h1) {
            double i1 = 1.0 / u1;
            #pragma unroll
            for (int w = 0; w < WAYS; ++w) p1[w] *= i1;
            up1 = u1;
          }
          // column balance
          #pragma unroll
          for (int w = 0; w < WAYS; ++w) {
            double s = wsum64d(p0[w] + (h1 ? p1[w] : 0.0));
            double f = cval / s;
            p0[w] *= f;
            if (h1) p1[w] *= f;
          }
          // clamp labeled rows (only r0 can be < NSUP since NSUP <= 64)
          if (clamp && r0 < NSUP) {
            #pragma unroll
            for (int w = 0; w < WAYS; ++w) p0[w] = (ysq == w) ? 1.0 : 0.0;
          }
          ++m;
          // convergence check values for iteration m
          u0 = p0[0] + p0[1] + p0[2] + p0[3] + p0[4];
          if (h1) u1 = p1[0] + p1[1] + p1[2] + p1[3] + p1[4];
          double dl = fabs(up0 - u0);
          if (h1) dl = fmax(dl, fabs(up1 - u1));
          dcur = wmax64d(dl);
        }
        if (ln == 0) mloc[q] = (unsigned)m;
      }
      __syncthreads();
      if (t == 0) {
        unsigned lm = mloc[0] > mloc[1] ? mloc[0] : mloc[1];
        atomicMax(&tmax[rnd], lm);
        __hip_atomic_fetch_add(&arr[rnd], 1u, __ATOMIC_ACQ_REL, __HIP_MEMORY_SCOPE_AGENT);
        long sp = 0;
        for (;;) {
          unsigned v = __hip_atomic_load(&arr[rnd], __ATOMIC_ACQUIRE, __HIP_MEMORY_SCOPE_AGENT);
          if (v >= (unsigned)NB2) break;
          __builtin_amdgcn_s_sleep(1);
          if (++sp > 50000000L) break;   // safety: terminate, don't hang
        }
        Tsh = __hip_atomic_load(&tmax[rnd], __ATOMIC_RELAXED, __HIP_MEMORY_SCOPE_AGENT);
      }
      __syncthreads();
      ++rnd;
      unsigned T = Tsh;
      if (T == target) break;   // nobody advanced past target -> K = target
      target = T;
    }
    if (own) {
      #pragma unroll
      for (int w = 0; w < WAYS; ++w) {
        Z[q][(base + r0) * WAYS + w] = p0[w];
        if (h1) Z[q][(base + r1) * WAYS + w] = p1[w];
      }
    }
    __syncthreads();
  };

  for (int epi = 0; epi <= NEPOCH; ++epi) {
    // ---- Pq rows 25..99 per episode ----
    for (int q = 0; q < EPB; ++q) {
      for (int e = t; e < WAYS * DIM; e += 256) buf[e] = protA[q][e];
      __syncthreads();
      for (int w = wv; w < WAYS; w += 4) {
        double s = 0.0;
        #pragma unroll
        for (int mm = 0; mm < DIM / 64; ++mm) {
          double p = buf[w * DIM + ln + 64 * mm];
          s = fma(p, p, s);
        }
        s = wsum64d(s);
        if (ln == 0) pn[w] = s;
      }
      __syncthreads();
      for (int r = NSUP + wv; r < NN; r += 4) {
        double a0 = 0, a1 = 0, a2 = 0, a3 = 0, a4 = 0;
        #pragma unroll
        for (int mm = 0; mm < DIM / 64; ++mm) {
          int k = ln + 64 * mm;
          double f = featA[q][r * DIM + k];
          a0 = fma(f, buf[0 * DIM + k], a0);
          a1 = fma(f, buf[1 * DIM + k], a1);
          a2 = fma(f, buf[2 * DIM + k], a2);
          a3 = fma(f, buf[3 * DIM + k], a3);
          a4 = fma(f, buf[4 * DIM + k], a4);
        }
        a0 = wsum64d(a0); a1 = wsum64d(a1); a2 = wsum64d(a2);
        a3 = wsum64d(a3); a4 = wsum64d(a4);
        if (ln == 0) {
          double nr = nrmA[q][r];
          double d0 = (nr + pn[0]) - 2.0 * a0;
          double d1 = (nr + pn[1]) - 2.0 * a1;
          double d2 = (nr + pn[2]) - 2.0 * a2;
          double d3 = (nr + pn[3]) - 2.0 * a3;
          double d4 = (nr + pn[4]) - 2.0 * a4;
          Z[q][r * WAYS + 0] = exp(-10.0 * (d0 > 0.0 ? d0 : 0.0));
          Z[q][r * WAYS + 1] = exp(-10.0 * (d1 > 0.0 ? d1 : 0.0));
          Z[q][r * WAYS + 2] = exp(-10.0 * (d2 > 0.0 ? d2 : 0.0));
          Z[q][r * WAYS + 3] = exp(-10.0 * (d3 > 0.0 ? d3 : 0.0));
          Z[q][r * WAYS + 4] = exp(-10.0 * (d4 > 0.0 ? d4 : 0.0));
        }
      }
      __syncthreads();
    }
    sinkhorn(NSUP, NQ, 15.0, false);

    if (epi == NEPOCH) {
      if (t < EPB) rediA[t] = 0;
      __syncthreads();
      for (int e = t; e < EPB * NQ; e += 256) {
        int q = e / NQ, i = e % NQ;
        int row = NSUP + i;
        double bv = Z[q][row * WAYS + 0]; int am = 0;
        #pragma unroll
        for (int w = 1; w < WAYS; ++w) {
          double v = Z[q][row * WAYS + w];
          if (v > bv) { bv = v; am = w; }
        }
        if (am == yq[(b * EPB + q) * NQ + i]) atomicAdd(&rediA[q], 1);
      }
      __syncthreads();
      if (t < EPB) out[b * EPB + t] = (float)((double)rediA[t] / 75.0);
    } else {
      // one-hot support rows
      for (int e = t; e < EPB * NSUP; e += 256) {
        int q = e / NSUP, i = e % NSUP;
        #pragma unroll
        for (int w = 0; w < WAYS; ++w) Z[q][i * WAYS + w] = (ysS[q][i] == w) ? 1.0 : 0.0;
      }
      __syncthreads();
      // Zn = Inv @ Z : wave pair (wv>>1 = episode), row parity wv&1
      {
        int q = wv >> 1;
        for (int r = (wv & 1); r < NN; r += 2) {
          double a0 = 0, a1 = 0, a2 = 0, a3 = 0, a4 = 0;
          for (int k = ln; k < NN; k += 64) {
            double iv = InvA[q][r * NN + k];
            a0 = fma(iv, Z[q][k * WAYS + 0], a0);
            a1 = fma(iv, Z[q][k * WAYS + 1], a1);
            a2 = fma(iv, Z[q][k * WAYS + 2], a2);
            a3 = fma(iv, Z[q][k * WAYS + 3], a3);
            a4 = fma(iv, Z[q][k * WAYS + 4], a4);
          }
          a0 = wsum64d(a0); a1 = wsum64d(a1); a2 = wsum64d(a2);
          a3 = wsum64d(a3); a4 = wsum64d(a4);
          if (ln == 0) {
            buf[q * (NN * WAYS) + r * WAYS + 0] = a0;
            buf[q * (NN * WAYS) + r * WAYS + 1] = a1;
            buf[q * (NN * WAYS) + r * WAYS + 2] = a2;
            buf[q * (NN * WAYS) + r * WAYS + 3] = a3;
            buf[q * (NN * WAYS) + r * WAYS + 4] = a4;
          }
        }
      }
      __syncthreads();
      for (int e = t; e < EPB * NN * WAYS; e += 256)
        Z[e / (NN * WAYS)][e % (NN * WAYS)] = buf[e];
      __syncthreads();
      sinkhorn(0, NN, 20.0, true);
      // column sums of final Z
      if (t < EPB * WAYS) {
        int q = t / WAYS, w = t % WAYS;
        double s = 0.0;
        for (int r = 0; r < NN; ++r) s += Z[q][r * WAYS + w];
        csv[q][w] = s;
      }
      __syncthreads();
      // proto = 0.4*proto + 0.6*(Z^T feat / colsum)
      for (int q = 0; q < EPB; ++q) {
        for (int d = t; d < DIM; d += 256) {
          double a0 = 0, a1 = 0, a2 = 0, a3 = 0, a4 = 0;
          for (int n = 0; n < NN; ++n) {
            double f = featA[q][n * DIM + d];
            a0 = fma(Z[q][n * WAYS + 0], f, a0);
            a1 = fma(Z[q][n * WAYS + 1], f, a1);
            a2 = fma(Z[q][n * WAYS + 2], f, a2);
            a3 = fma(Z[q][n * WAYS + 3], f, a3);
            a4 = fma(Z[q][n * WAYS + 4], f, a4);
          }
          double o, npv;
          npv = a0 / csv[q][0]; o = protA[q][0 * DIM + d]; protA[q][0 * DIM + d] = 0.4 * o + 0.6 * npv;
          npv = a1 / csv[q][1]; o = protA[q][1 * DIM + d]; protA[q][1 * DIM + d] = 0.4 * o + 0.6 * npv;
          npv = a2 / csv[q][2]; o = protA[q][2 * DIM + d]; protA[q][2 * DIM + d] = 0.4 * o + 0.6 * npv;
          npv = a3 / csv[q][3]; o = protA[q][3 * DIM + d]; protA[q][3 * DIM + d] = 0.4 * o + 0.6 * npv;
          npv = a4 / csv[q][4]; o = protA[q][4 * DIM + d]; protA[q][4 * DIM + d] = 0.4 * o + 0.6 * npv;
        }
      }
      __syncthreads();
    }
  }
}

extern "C" void kernel_launch(void* const* d_in, const int* in_sizes, int n_in,
                              void* d_out, int out_size, void* d_ws, size_t ws_size,
                              hipStream_t stream) {
  const float* xs = (const float*)d_in[0];
  const float* xq = (const float*)d_in[1];
  const int*   ys = (const int*)d_in[2];
  const int*   yq = (const int*)d_in[3];
  float* out = (float*)d_out;
  char* ws   = (char*)d_ws;

  hipMemsetAsync(d_ws, 0, CTRL_BYTES, stream);

  // opt in to >64KB dynamic LDS (idempotent; proven working in round 3)
  (void)hipFuncSetAttribute((const void*)k1_lds,
                            hipFuncAttributeMaxDynamicSharedMemorySize,
                            DYN_LDS_BYTES);
  hipLaunchKernelGGL(k1_lds, dim3(B_RUNS), dim3(512), DYN_LDS_BYTES, stream, xs, xq, ws);
  hipLaunchKernelGGL(k2_epochs, dim3(NB2), dim3(256), 0, stream, ys, yq, ws, out);
}

// Round 5
// 6074.968 us; speedup vs baseline: 2.8684x; 1.3241x over previous
//
#include <hip/hip_runtime.h>

// ---------------- problem constants ----------------
#define B_RUNS 500
#define WAYS   5
#define NSUP   25
#define NQ     75
#define NN     100
#define DIM    640
#define TOPK   6
#define KHOP   4
#define NEPOCH 10

// ---------------- barrier control region ----------------
#define CTRL_BYTES 262144
#define NBK    20                 // buckets
#define BPB    25                 // blocks per bucket (500/20)
#define NROUND 1024

// per-episode (doubles): feat [100*640] (first 10000 become G_f at end) | Inv [100*100]
#define EP_DBL 74016              // padded; *8 = 592128 (256-aligned)
#define FEAT_OFF 0
#define INV_OFF  64000

#define DYN_LDS_DBL  16400        // A (10000) + ST (6400)
#define DYN_LDS_BYTES (DYN_LDS_DBL * 8)   // 131200

__device__ __forceinline__ double wsum64d(double v) {
  #pragma unroll
  for (int off = 32; off > 0; off >>= 1) v += __shfl_xor(v, off, 64);
  return v;
}
__device__ __forceinline__ double wmax64d(double v) {
  #pragma unroll
  for (int off = 32; off > 0; off >>= 1) v = fmax(v, __shfl_xor(v, off, 64));
  return v;
}

// 2-level grid barrier + global max of payload. Requires all 500 blocks co-resident.
__device__ unsigned grid_barrier_max(unsigned* ctrlu, int b, unsigned rnd, unsigned lm) {
  unsigned r = rnd < (NROUND - 1) ? rnd : (NROUND - 1);
  int bk = b % NBK;
  unsigned* barr = ctrlu + bk * NROUND + r;
  unsigned* bmax = ctrlu + (NBK + bk) * NROUND + r;
  unsigned* marr = ctrlu + 2 * NBK * NROUND + r;
  unsigned* mmax = ctrlu + 2 * NBK * NROUND + NROUND + r;
  atomicMax(bmax, lm);
  unsigned a = __hip_atomic_fetch_add(barr, 1u, __ATOMIC_ACQ_REL, __HIP_MEMORY_SCOPE_AGENT);
  if (a == (unsigned)(BPB - 1)) {
    unsigned bm = __hip_atomic_load(bmax, __ATOMIC_RELAXED, __HIP_MEMORY_SCOPE_AGENT);
    atomicMax(mmax, bm);
    __hip_atomic_fetch_add(marr, 1u, __ATOMIC_ACQ_REL, __HIP_MEMORY_SCOPE_AGENT);
  }
  long sp = 0;
  while (__hip_atomic_load(marr, __ATOMIC_ACQUIRE, __HIP_MEMORY_SCOPE_AGENT) < (unsigned)NBK) {
    __builtin_amdgcn_s_sleep(2);
    if (++sp > 20000000L) break;   // safety: terminate, don't hang
  }
  return __hip_atomic_load(mmax, __ATOMIC_RELAXED, __HIP_MEMORY_SCOPE_AGENT);
}

// =====================================================================
// Kernel 1: 512 threads/episode. gram (b128 k-pairs, split-K teams) +
// top-6 sparse extract + sparse L@(L@X) feat update + hop-3 dense chain
// (L^2, build_graph^2, M, Gauss-Jordan) + final gram G_f.
// =====================================================================
__global__ __launch_bounds__(512) void k1_lds(const float* __restrict__ xs,
                                              const float* __restrict__ xq,
                                              char* __restrict__ wsb) {
  extern __shared__ double dynb[];
  double* A  = dynb;            // 100x100
  double* ST = dynb + 10000;    // staging (gram: 2x1616; sparse: Xs 3200 + Ts 3200)
  double* Xs = ST;
  double* Ts = ST + 3200;

  const int b = blockIdx.x;
  double* ep   = (double*)(wsb + CTRL_BYTES) + (size_t)b * EP_DBL;
  double* feat = ep + FEAT_OFF;
  double* Inv  = ep + INV_OFF;
  double* Gf   = ep;            // aliases feat start; written only at the very end

  __shared__ double nsh[NN], Dsh[NN], rowk[NN], colk[NN];
  __shared__ double wS[NN][7];
  __shared__ int    idxS[NN][7];
  __shared__ int    cntS[NN];

  const int t  = threadIdx.x;
  const int tm = t >> 8;              // team 0/1
  const int tt = t & 255;
  const int tx = tt & 15, ty = tt >> 4;
  double* STt = ST + tm * 1616;

  int ia[7], ja[7];
  #pragma unroll
  for (int a = 0; a < 7; ++a) { int v = ty + 16 * a; ia[a] = v < NN ? v : NN - 1; }
  #pragma unroll
  for (int a = 0; a < 7; ++a) { int v = tx + 16 * a; ja[a] = v < NN ? v : NN - 1; }
  int ia2[4];
  #pragma unroll
  for (int a = 0; a < 4; ++a) { int rr = ty + 16 * a; ia2[a] = tm * 50 + (rr < 50 ? rr : 49); }
  // sparse-update mapping: sx in [0,16) col-pair, sy in [0,32) row base
  const int sx = t & 15, sy = t >> 4;

  const float* xsb = xs + (size_t)b * NSUP * DIM;
  const float* xqb = xq + (size_t)b * NQ * DIM;
  for (int e = t; e < NSUP * DIM; e += 512) feat[e] = (double)xsb[e];
  for (int e = t; e < NQ * DIM; e += 512)  feat[NSUP * DIM + e] = (double)xqb[e];
  __syncthreads();

  // ---- gram: C = F F^T into A (split-K teams, b128 k-pair LDS reads) ----
  auto gram_to_A = [&]() {
    double acc[7][7];
    #pragma unroll
    for (int a = 0; a < 7; ++a)
      #pragma unroll
      for (int c = 0; c < 7; ++c) acc[a][c] = 0.0;
    for (int chunk = 0; chunk < 20; ++chunk) {
      int k0 = (chunk * 2 + tm) * 16;
      for (int e = tt; e < NN * 16; e += 256) {
        int r = e >> 4, km = e & 15;
        STt[(km >> 1) * 202 + 2 * r + (km & 1)] = feat[r * DIM + k0 + km];
      }
      __syncthreads();
      #pragma unroll 2
      for (int m = 0; m < 8; ++m) {
        double2 rv[7], cv[7];
        #pragma unroll
        for (int a = 0; a < 7; ++a) rv[a] = *(const double2*)(STt + m * 202 + 2 * ia[a]);
        #pragma unroll
        for (int c = 0; c < 7; ++c) cv[c] = *(const double2*)(STt + m * 202 + 2 * ja[c]);
        #pragma unroll
        for (int a = 0; a < 7; ++a)
          #pragma unroll
          for (int c = 0; c < 7; ++c) {
            acc[a][c] = fma(rv[a].x, cv[c].x, acc[a][c]);
            acc[a][c] = fma(rv[a].y, cv[c].y, acc[a][c]);
          }
      }
      __syncthreads();
    }
    // combine team partials (team0 first operand, as validated in round 4)
    if (tm == 1) {
      #pragma unroll
      for (int a = 0; a < 7; ++a)
        #pragma unroll
        for (int c = 0; c < 7; ++c) {
          int i = ty + 16 * a, j = tx + 16 * c;
          if (i < NN && j < NN) A[i * NN + j] = acc[a][c];
        }
    }
    __syncthreads();
    if (tm == 0) {
      #pragma unroll
      for (int a = 0; a < 7; ++a)
        #pragma unroll
        for (int c = 0; c < 7; ++c) {
          int i = ty + 16 * a, j = tx + 16 * c;
          if (i < NN && j < NN) A[i * NN + j] = acc[a][c] + A[i * NN + j];
        }
    }
    __syncthreads();
  };

  for (int hop = 0; hop < KHOP; ++hop) {
    gram_to_A();
    if (t < NN) nsh[t] = A[t * NN + t];
    __syncthreads();
    // A = exp(-10 * max(ni+nj-2c, 0))
    for (int e = t; e < NN * NN; e += 512) {
      int i = e / NN, j = e % NN;
      double d = (nsh[i] + nsh[j]) - 2.0 * A[e];
      d = d > 0.0 ? d : 0.0;
      A[e] = exp(-10.0 * d);
    }
    __syncthreads();
    // ---- top-6 per row (ties -> lowest index), zero rest, rowsum, Dsh ----
    unsigned long long m0 = 0ull, m1 = 0ull;
    if (t < NN) {
      for (int s = 0; s < TOPK; ++s) {
        double best = -1.0; int bj = 0;
        for (int j = 0; j < NN; ++j) {
          unsigned long long bit = (j < 64) ? ((m0 >> j) & 1ull) : ((m1 >> (j - 64)) & 1ull);
          if (bit) continue;
          double v = A[t * NN + j];
          if (v > best) { best = v; bj = j; }
        }
        if (bj < 64) m0 |= 1ull << bj; else m1 |= 1ull << (bj - 64);
      }
      for (int j = 0; j < NN; ++j) {
        unsigned long long bit = (j < 64) ? ((m0 >> j) & 1ull) : ((m1 >> (j - 64)) & 1ull);
        if (!bit) A[t * NN + j] = 0.0;
      }
      double s = 0.0;
      for (int j = 0; j < NN; ++j) s += A[t * NN + j];
      Dsh[t] = 1.0 / sqrt(s);
    }
    __syncthreads();
    // ---- extract sparse L row: ascending index, self term folded/inserted ----
    if (t < NN) {
      int cnt = 0; bool sd = false;
      for (int j = 0; j < NN; ++j) {
        unsigned long long bit = (j < 64) ? ((m0 >> j) & 1ull) : ((m1 >> (j - 64)) & 1ull);
        if (!bit) continue;
        double w_ = (Dsh[j] * A[t * NN + j]) * Dsh[t];
        double lw = 0.5 * w_;
        if (j == t) { lw = 0.5 + lw; sd = true; }
        else if (!sd && j > t) { idxS[t][cnt] = t; wS[t][cnt] = 0.5; ++cnt; sd = true; }
        idxS[t][cnt] = j; wS[t][cnt] = lw; ++cnt;
      }
      if (!sd) { idxS[t][cnt] = t; wS[t][cnt] = 0.5; ++cnt; }
      cntS[t] = cnt;
    }
    __syncthreads();
    if (hop == KHOP - 1) {
      // dense L into A (needed for L^2 -> W)
      for (int e = t; e < NN * NN; e += 512) {
        int i = e / NN, j = e % NN;
        double w = (Dsh[j] * A[e]) * Dsh[i];
        A[e] = ((i == j) ? 0.5 : 0.0) + 0.5 * w;
      }
      __syncthreads();
    }
    // ---- feat = L @ (L @ feat), sparse, 32-col blocks via ST only ----
    for (int c0 = 0; c0 < DIM; c0 += 32) {
      for (int e = t; e < NN * 32; e += 512) {
        int r = e >> 5, c = e & 31;
        Xs[e] = feat[r * DIM + c0 + c];
      }
      __syncthreads();
      #pragma unroll
      for (int a = 0; a < 4; ++a) {
        int r = sy + 32 * a;
        if (r < NN) {
          int cnt = cntS[r];
          double s0 = 0.0, s1 = 0.0;
          for (int s = 0; s < cnt; ++s) {
            int j = idxS[r][s]; double w = wS[r][s];
            double2 xv = *(const double2*)(Xs + j * 32 + 2 * sx);
            s0 = fma(w, xv.x, s0); s1 = fma(w, xv.y, s1);
          }
          Ts[r * 32 + 2 * sx] = s0; Ts[r * 32 + 2 * sx + 1] = s1;
        }
      }
      __syncthreads();
      #pragma unroll
      for (int a = 0; a < 4; ++a) {
        int r = sy + 32 * a;
        if (r < NN) {
          int cnt = cntS[r];
          double s0 = 0.0, s1 = 0.0;
          for (int s = 0; s < cnt; ++s) {
            int j = idxS[r][s]; double w = wS[r][s];
            double2 tv = *(const double2*)(Ts + j * 32 + 2 * sx);
            s0 = fma(w, tv.x, s0); s1 = fma(w, tv.y, s1);
          }
          double2 o; o.x = s0; o.y = s1;
          *(double2*)(feat + r * DIM + c0 + 2 * sx) = o;
        }
      }
      __syncthreads();
    }

    if (hop == KHOP - 1) {
      // ---- G = L @ L (row-split teams), overwrite A ----
      {
        double gg[4][7];
        #pragma unroll
        for (int a = 0; a < 4; ++a)
          #pragma unroll
          for (int c = 0; c < 7; ++c) gg[a][c] = 0.0;
        for (int k = 0; k < NN; ++k) {
          double rv[4], cv[7];
          #pragma unroll
          for (int a = 0; a < 4; ++a) rv[a] = A[ia2[a] * NN + k];
          #pragma unroll
          for (int c = 0; c < 7; ++c) cv[c] = A[k * NN + ja[c]];
          #pragma unroll
          for (int a = 0; a < 4; ++a)
            #pragma unroll
            for (int c = 0; c < 7; ++c) gg[a][c] = fma(rv[a], cv[c], gg[a][c]);
        }
        __syncthreads();
        #pragma unroll
        for (int a = 0; a < 4; ++a)
          #pragma unroll
          for (int c = 0; c < 7; ++c) {
            int rr = ty + 16 * a, j = tx + 16 * c;
            if (rr < 50 && j < NN) A[(tm * 50 + rr) * NN + j] = gg[a][c];
          }
        __syncthreads();
      }
      // ---- W = build_graph(build_graph(G)) ----
      for (int rep = 0; rep < 2; ++rep) {
        if (t < NN) A[t * NN + t] = 0.0;
        __syncthreads();
        if (t < NN) {
          double s = 0.0;
          for (int j = 0; j < NN; ++j) s += A[t * NN + j];
          Dsh[t] = 1.0 / sqrt(s);
        }
        __syncthreads();
        for (int e = t; e < NN * NN; e += 512) {
          int i = e / NN, j = e % NN;
          A[e] = (Dsh[j] * A[e]) * Dsh[i];
        }
        __syncthreads();
      }
      // M = I - 0.7*W
      for (int e = t; e < NN * NN; e += 512) {
        int i = e / NN, j = e % NN;
        A[e] = ((i == j) ? 1.0 : 0.0) - 0.7 * A[e];
      }
      __syncthreads();
      // ---- Gauss-Jordan sweep inverse in LDS ----
      for (int k = 0; k < NN; ++k) {
        if (t < NN) { rowk[t] = A[k * NN + t]; colk[t] = A[t * NN + k]; }
        __syncthreads();
        double pinv = 1.0 / rowk[k];
        for (int e = t; e < NN * NN; e += 512) {
          int i = e / NN, j = e % NN;
          double v;
          if (i == k)      v = (j == k) ? pinv : rowk[j] * pinv;
          else if (j == k) v = -(colk[i] * pinv);
          else             v = A[e] - colk[i] * (rowk[j] * pinv);
          A[e] = v;
        }
        __syncthreads();
      }
      for (int e = t; e < NN * NN; e += 512) Inv[e] = A[e];
      __syncthreads();
    }
  }
  // ---- final gram of updated features -> G_f (overwrites dead feat head) ----
  gram_to_A();
  for (int e = t; e < NN * NN; e += 512) Gf[e] = A[e];
}

// =====================================================================
// Kernel 2: 500 blocks x 256 thr (2 blocks/CU). beta-space epochs:
// gv = G_f * beta, dist from gram, register-wave Sinkhorn with decoupled
// convergence + 2-level grid barrier.
// =====================================================================
__global__ __launch_bounds__(256, 2) void k2_epochs(const int* __restrict__ ys,
                                                    const int* __restrict__ yq,
                                                    char* __restrict__ wsb,
                                                    float* __restrict__ out) {
  const int b = blockIdx.x;
  const double* G   = (const double*)(wsb + CTRL_BYTES) + (size_t)b * EP_DBL;
  const double* Inv = G + INV_OFF;
  unsigned* ctrlu = (unsigned*)wsb;

  __shared__ double Z[NN * WAYS];
  __shared__ double gvF[WAYS * NN];        // gv[w*100+n]
  __shared__ double pbuf[4][WAYS * NN];    // per-wave partials / Zn temp
  __shared__ double betaS[WAYS][NN];
  __shared__ double nrmS[NN];
  __shared__ double csv[WAYS], pnS[WAYS];
  __shared__ int ysS[NSUP];
  __shared__ unsigned Tsh;
  __shared__ int redi;

  const int t  = threadIdx.x;
  const int wv = t >> 6, ln = t & 63;
  unsigned rnd = 0;

  if (t < NSUP) ysS[t] = ys[b * NSUP + t];
  if (t < NN)   nrmS[t] = G[t * NN + t];
  for (int e = t; e < WAYS * NN; e += 256) {
    int w = e / NN, n = e % NN;
    betaS[w][n] = (n >= w * 5 && n < w * 5 + 5) ? 0.2 : 0.0;
  }
  __syncthreads();

  auto sinkhorn = [&](int base, int n, double cval, bool clamp) {
    const bool own = (wv == 0);
    const int r0 = ln, r1 = ln + 64;
    const bool h1 = (r1 < n);
    double p0[WAYS], p1[WAYS];
    double up0 = 0.0, up1 = 0.0, u0 = 0.0, u1 = 0.0, dcur = 0.0;
    int m = 0; int ysq = -1;
    if (own) {
      #pragma unroll
      for (int w = 0; w < WAYS; ++w) {
        p0[w] = Z[(base + r0) * WAYS + w];
        p1[w] = h1 ? Z[(base + r1) * WAYS + w] : 0.0;
      }
      if (clamp && r0 < NSUP) ysq = ysS[r0];
      u0 = p0[0] + p0[1] + p0[2] + p0[3] + p0[4];
      if (h1) u1 = p1[0] + p1[1] + p1[2] + p1[3] + p1[4];
      double dl = fabs(up0 - u0);
      if (h1) dl = fmax(dl, fabs(up1 - u1));
      dcur = wmax64d(dl);
    }
    unsigned target = 0;
    for (;;) {
      if (own) {
        while (m < 1000 && ((unsigned)m < target || dcur > 1e-3)) {
          double i0 = 1.0 / u0;
          #pragma unroll
          for (int w = 0; w < WAYS; ++w) p0[w] *= i0;
          up0 = u0;
          if (h1) {
            double i1 = 1.0 / u1;
            #pragma unroll
            for (int w = 0; w < WAYS; ++w) p1[w] *= i1;
            up1 = u1;
          }
          #pragma unroll
          for (int w = 0; w < WAYS; ++w) {
            double s = wsum64d(p0[w] + (h1 ? p1[w] : 0.0));
            double f = cval / s;
            p0[w] *= f;
            if (h1) p1[w] *= f;
          }
          if (clamp && r0 < NSUP) {
            #pragma unroll
            for (int w = 0; w < WAYS; ++w) p0[w] = (ysq == w) ? 1.0 : 0.0;
          }
          ++m;
          u0 = p0[0] + p0[1] + p0[2] + p0[3] + p0[4];
          if (h1) u1 = p1[0] + p1[1] + p1[2] + p1[3] + p1[4];
          double dl = fabs(up0 - u0);
          if (h1) dl = fmax(dl, fabs(up1 - u1));
          dcur = wmax64d(dl);
        }
      }
      __syncthreads();
      if (t == 0) Tsh = grid_barrier_max(ctrlu, b, rnd, (unsigned)m);
      __syncthreads();
      ++rnd;
      unsigned T = Tsh;
      if (T == target) break;
      target = T;
    }
    if (own) {
      #pragma unroll
      for (int w = 0; w < WAYS; ++w) {
        Z[(base + r0) * WAYS + w] = p0[w];
        if (h1) Z[(base + r1) * WAYS + w] = p1[w];
      }
    }
    __syncthreads();
  };

  for (int epi = 0; epi <= NEPOCH; ++epi) {
    // ---- gv[w][r] = sum_k G[r][k]*beta[w][k]  (G symmetric; k split over waves) ----
    {
      double a0[WAYS], a1[WAYS];
      #pragma unroll
      for (int w = 0; w < WAYS; ++w) { a0[w] = 0.0; a1[w] = 0.0; }
      int k0 = wv * 25;
      for (int kk = 0; kk < 25; ++kk) {
        int k = k0 + kk;
        double g0 = G[(size_t)k * NN + ln];
        double g1 = (ln < NN - 64) ? G[(size_t)k * NN + 64 + ln] : 0.0;
        #pragma unroll
        for (int w = 0; w < WAYS; ++w) {
          double bw = betaS[w][k];
          a0[w] = fma(g0, bw, a0[w]);
          a1[w] = fma(g1, bw, a1[w]);
        }
      }
      #pragma unroll
      for (int w = 0; w < WAYS; ++w) {
        pbuf[wv][w * NN + ln] = a0[w];
        if (ln < NN - 64) pbuf[wv][w * NN + 64 + ln] = a1[w];
      }
    }
    __syncthreads();
    for (int e = t; e < WAYS * NN; e += 256)
      gvF[e] = ((pbuf[0][e] + pbuf[1][e]) + pbuf[2][e]) + pbuf[3][e];
    __syncthreads();
    if (t < WAYS) {
      double s = 0.0;
      for (int n = 0; n < NN; ++n) s = fma(betaS[t][n], gvF[t * NN + n], s);
      pnS[t] = s;
    }
    __syncthreads();
    // ---- Pq rows 25..99 ----
    for (int e = t; e < NQ * WAYS; e += 256) {
      int r = NSUP + e / WAYS, w = e % WAYS;
      double d = (nrmS[r] + pnS[w]) - 2.0 * gvF[w * NN + r];
      Z[r * WAYS + w] = exp(-10.0 * (d > 0.0 ? d : 0.0));
    }
    __syncthreads();
    sinkhorn(NSUP, NQ, 15.0, false);

    if (epi == NEPOCH) {
      if (t == 0) redi = 0;
      __syncthreads();
      if (t < NQ) {
        int row = NSUP + t;
        double bv = Z[row * WAYS + 0]; int am = 0;
        #pragma unroll
        for (int w = 1; w < WAYS; ++w) {
          double v = Z[row * WAYS + w];
          if (v > bv) { bv = v; am = w; }
        }
        if (am == yq[b * NQ + t]) atomicAdd(&redi, 1);
      }
      __syncthreads();
      if (t == 0) out[b] = (float)((double)redi / 75.0);
    } else {
      if (t < NSUP) {
        #pragma unroll
        for (int w = 0; w < WAYS; ++w) Z[t * WAYS + w] = (ysS[t] == w) ? 1.0 : 0.0;
      }
      __syncthreads();
      // Zn = Inv @ Z (waves over rows, butterfly k-reduction)
      for (int r = wv; r < NN; r += 4) {
        double a0 = 0, a1 = 0, a2 = 0, a3 = 0, a4 = 0;
        for (int k = ln; k < NN; k += 64) {
          double iv = Inv[(size_t)r * NN + k];
          a0 = fma(iv, Z[k * WAYS + 0], a0);
          a1 = fma(iv, Z[k * WAYS + 1], a1);
          a2 = fma(iv, Z[k * WAYS + 2], a2);
          a3 = fma(iv, Z[k * WAYS + 3], a3);
          a4 = fma(iv, Z[k * WAYS + 4], a4);
        }
        a0 = wsum64d(a0); a1 = wsum64d(a1); a2 = wsum64d(a2);
        a3 = wsum64d(a3); a4 = wsum64d(a4);
        if (ln == 0) {
          pbuf[0][r * WAYS + 0] = a0; pbuf[0][r * WAYS + 1] = a1;
          pbuf[0][r * WAYS + 2] = a2; pbuf[0][r * WAYS + 3] = a3;
          pbuf[0][r * WAYS + 4] = a4;
        }
      }
      __syncthreads();
      for (int e = t; e < NN * WAYS; e += 256) Z[e] = pbuf[0][e];
      __syncthreads();
      sinkhorn(0, NN, 20.0, true);
      if (t < WAYS) {
        double s = 0.0;
        for (int r = 0; r < NN; ++r) s += Z[r * WAYS + t];
        csv[t] = s;
      }
      __syncthreads();
      // beta' = 0.4*beta + 0.6 * Z[:,w]/csv[w]
      for (int e = t; e < NN * WAYS; e += 256) {
        int n = e / WAYS, w = e % WAYS;
        double nb = Z[n * WAYS + w] / csv[w];
        betaS[w][n] = 0.4 * betaS[w][n] + 0.6 * nb;
      }
      __syncthreads();
    }
  }
}

extern "C" void kernel_launch(void* const* d_in, const int* in_sizes, int n_in,
                              void* d_out, int out_size, void* d_ws, size_t ws_size,
                              hipStream_t stream) {
  const float* xs = (const float*)d_in[0];
  const float* xq = (const float*)d_in[1];
  const int*   ys = (const int*)d_in[2];
  const int*   yq = (const int*)d_in[3];
  float* out = (float*)d_out;
  char* ws   = (char*)d_ws;

  hipMemsetAsync(d_ws, 0, CTRL_BYTES, stream);

  (void)hipFuncSetAttribute((const void*)k1_lds,
                            hipFuncAttributeMaxDynamicSharedMemorySize,
                            DYN_LDS_BYTES);
  hipLaunchKernelGGL(k1_lds, dim3(B_RUNS), dim3(512), DYN_LDS_BYTES, stream, xs, xq, ws);
  hipLaunchKernelGGL(k2_epochs, dim3(B_RUNS), dim3(256), 0, stream, ys, yq, ws, out);
}

// Round 6
// 4398.722 us; speedup vs baseline: 3.9614x; 1.3811x over previous
//
#include <hip/hip_runtime.h>

// ---------------- problem constants ----------------
#define B_RUNS 500
#define WAYS   5
#define NSUP   25
#define NQ     75
#define NN     100
#define DIM    640
#define TOPK   6
#define KHOP   4
#define NEPOCH 10

// ---------------- barrier control region ----------------
#define CTRL_BYTES 262144
#define NBK    20                 // buckets
#define BPB    25                 // blocks per bucket (500/20)
#define NROUND 1024

// per-episode doubles: Gf [10000] | Inv [10000] | R scratch [10000]
#define EP_DBL   30016            // padded (×8 = 240128, 256-aligned)
#define GF_OFF   0
#define INV_OFF  10000
#define R_OFF    20000

#define DYN_LDS_DBL  (10000 + 3232)       // G (100x100) + 2-team gram staging
#define DYN_LDS_BYTES (DYN_LDS_DBL * 8)   // 105856 B

__device__ __forceinline__ double wsum64d(double v) {
  #pragma unroll
  for (int off = 32; off > 0; off >>= 1) v += __shfl_xor(v, off, 64);
  return v;
}
__device__ __forceinline__ double wmax64d(double v) {
  #pragma unroll
  for (int off = 32; off > 0; off >>= 1) v = fmax(v, __shfl_xor(v, off, 64));
  return v;
}

// 2-level grid barrier + global max of payload. Requires all 500 blocks co-resident.
__device__ unsigned grid_barrier_max(unsigned* ctrlu, int b, unsigned rnd, unsigned lm) {
  unsigned r = rnd < (NROUND - 1) ? rnd : (NROUND - 1);
  int bk = b % NBK;
  unsigned* barr = ctrlu + bk * NROUND + r;
  unsigned* bmax = ctrlu + (NBK + bk) * NROUND + r;
  unsigned* marr = ctrlu + 2 * NBK * NROUND + r;
  unsigned* mmax = ctrlu + 2 * NBK * NROUND + NROUND + r;
  atomicMax(bmax, lm);
  unsigned a = __hip_atomic_fetch_add(barr, 1u, __ATOMIC_ACQ_REL, __HIP_MEMORY_SCOPE_AGENT);
  if (a == (unsigned)(BPB - 1)) {
    unsigned bm = __hip_atomic_load(bmax, __ATOMIC_RELAXED, __HIP_MEMORY_SCOPE_AGENT);
    atomicMax(mmax, bm);
    __hip_atomic_fetch_add(marr, 1u, __ATOMIC_ACQ_REL, __HIP_MEMORY_SCOPE_AGENT);
  }
  long sp = 0;
  while (__hip_atomic_load(marr, __ATOMIC_ACQUIRE, __HIP_MEMORY_SCOPE_AGENT) < (unsigned)NBK) {
    __builtin_amdgcn_s_sleep(2);
    if (++sp > 20000000L) break;   // safety: terminate, don't hang
  }
  return __hip_atomic_load(mmax, __ATOMIC_RELAXED, __HIP_MEMORY_SCOPE_AGENT);
}

// =====================================================================
// Kernel 1 (gram-space): one initial fp64 gram from fp32 inputs, then
// per hop: top-6 by clamped distance -> sparse L -> G = L(LGL^T)L^T via
// global R scratch. Hop 3: write Gf, dense L^2 (sparse scatter), W chain,
// M = I-0.7W, Gauss-Jordan inverse -> Inv. Features never stored.
// =====================================================================
__global__ __launch_bounds__(512) void k1_lds(const float* __restrict__ xs,
                                              const float* __restrict__ xq,
                                              char* __restrict__ wsb) {
  extern __shared__ double dynb[];
  double* G  = dynb;            // 100x100
  double* ST = dynb + 10000;    // 2 teams x 1616 gram staging

  const int b = blockIdx.x;
  double* ep  = (double*)(wsb + CTRL_BYTES) + (size_t)b * EP_DBL;
  double* Gf  = ep + GF_OFF;
  double* Inv = ep + INV_OFF;
  double* R   = ep + R_OFF;

  __shared__ double nsh[NN], Dsh[NN], rowk[NN], colk[NN];
  __shared__ double wS[NN][7];
  __shared__ int    idxS[NN][7];
  __shared__ int    cntS[NN];

  const int t  = threadIdx.x;
  const int tm = t >> 8;              // team 0/1
  const int tt = t & 255;
  const int tx = tt & 15, ty = tt >> 4;
  double* STt = ST + tm * 1616;

  int ia[7], ja[7];
  #pragma unroll
  for (int a = 0; a < 7; ++a) { int v = ty + 16 * a; ia[a] = v < NN ? v : NN - 1; }
  #pragma unroll
  for (int a = 0; a < 7; ++a) { int v = tx + 16 * a; ja[a] = v < NN ? v : NN - 1; }

  // ---- initial gram G0 = F F^T from fp32 inputs (2-team split-K, b128 pairs) ----
  {
    double acc[7][7];
    #pragma unroll
    for (int a = 0; a < 7; ++a)
      #pragma unroll
      for (int c = 0; c < 7; ++c) acc[a][c] = 0.0;
    const float* xsb = xs + (size_t)b * NSUP * DIM;
    const float* xqb = xq + (size_t)b * NQ * DIM;
    for (int chunk = 0; chunk < 20; ++chunk) {
      int k0 = (chunk * 2 + tm) * 16;
      for (int e = tt; e < NN * 16; e += 256) {
        int r = e >> 4, km = e & 15;
        int k = k0 + km;
        float v = (r < NSUP) ? xsb[r * DIM + k] : xqb[(r - NSUP) * DIM + k];
        STt[(km >> 1) * 202 + 2 * r + (km & 1)] = (double)v;
      }
      __syncthreads();
      #pragma unroll 2
      for (int m = 0; m < 8; ++m) {
        double2 rv[7], cv[7];
        #pragma unroll
        for (int a = 0; a < 7; ++a) rv[a] = *(const double2*)(STt + m * 202 + 2 * ia[a]);
        #pragma unroll
        for (int c = 0; c < 7; ++c) cv[c] = *(const double2*)(STt + m * 202 + 2 * ja[c]);
        #pragma unroll
        for (int a = 0; a < 7; ++a)
          #pragma unroll
          for (int c = 0; c < 7; ++c) {
            acc[a][c] = fma(rv[a].x, cv[c].x, acc[a][c]);
            acc[a][c] = fma(rv[a].y, cv[c].y, acc[a][c]);
          }
      }
      __syncthreads();
    }
    if (tm == 1) {
      #pragma unroll
      for (int a = 0; a < 7; ++a)
        #pragma unroll
        for (int c = 0; c < 7; ++c) {
          int i = ty + 16 * a, j = tx + 16 * c;
          if (i < NN && j < NN) G[i * NN + j] = acc[a][c];
        }
    }
    __syncthreads();
    if (tm == 0) {
      #pragma unroll
      for (int a = 0; a < 7; ++a)
        #pragma unroll
        for (int c = 0; c < 7; ++c) {
          int i = ty + 16 * a, j = tx + 16 * c;
          if (i < NN && j < NN) G[i * NN + j] = acc[a][c] + G[i * NN + j];
        }
    }
    __syncthreads();
  }

  for (int hop = 0; hop < KHOP; ++hop) {
    if (t < NN) nsh[t] = G[t * NN + t];
    __syncthreads();
    // ---- top-6 per row by clamped distance (ascending; ties -> lowest index) ----
    int kj[TOPK]; double ke[TOPK];
    if (t < NN) {
      unsigned long long m0 = 0ull, m1 = 0ull;
      const double nt = nsh[t];
      for (int s = 0; s < TOPK; ++s) {
        double best = 1e300; int bj = 0;
        for (int j = 0; j < NN; ++j) {
          unsigned long long bit = (j < 64) ? ((m0 >> j) & 1ull) : ((m1 >> (j - 64)) & 1ull);
          if (bit) continue;
          double d = (nt + nsh[j]) - 2.0 * G[t * NN + j];
          d = d > 0.0 ? d : 0.0;
          if (d < best) { best = d; bj = j; }     // strict <: lowest index wins ties
        }
        if (bj < 64) m0 |= 1ull << bj; else m1 |= 1ull << (bj - 64);
      }
      // kept entries ascending (lowest set bit first); exp weights; rowsum
      double s = 0.0;
      unsigned long long mm0 = m0, mm1 = m1;
      #pragma unroll
      for (int sidx = 0; sidx < TOPK; ++sidx) {
        int j;
        if (mm0) { j = __ffsll((long long)mm0) - 1; mm0 &= mm0 - 1; }
        else     { j = 64 + __ffsll((long long)mm1) - 1; mm1 &= mm1 - 1; }
        double d = (nt + nsh[j]) - 2.0 * G[t * NN + j];
        d = d > 0.0 ? d : 0.0;
        double e = exp(-10.0 * d);
        kj[sidx] = j; ke[sidx] = e;
        s += e;
      }
      Dsh[t] = 1.0 / sqrt(s);
    }
    __syncthreads();
    // ---- build sparse L row: ascending index, self 0.5 folded/inserted ----
    if (t < NN) {
      int cnt = 0; bool sd = false;
      double dt = Dsh[t];
      #pragma unroll
      for (int sidx = 0; sidx < TOPK; ++sidx) {
        int j = kj[sidx];
        double lw = 0.5 * ((Dsh[j] * ke[sidx]) * dt);
        if (j == t) { lw = 0.5 + lw; sd = true; }
        else if (!sd && j > t) { idxS[t][cnt] = t; wS[t][cnt] = 0.5; ++cnt; sd = true; }
        idxS[t][cnt] = j; wS[t][cnt] = lw; ++cnt;
      }
      if (!sd) { idxS[t][cnt] = t; wS[t][cnt] = 0.5; ++cnt; }
      cntS[t] = cnt;
    }
    __syncthreads();
    // ---- congruence: G <- L (L G L^T) L^T via 4 sparse stages ----
    #pragma unroll 1
    for (int pair = 0; pair < 2; ++pair) {
      // R = L * G
      for (int e = t; e < NN * NN; e += 512) {
        int r = e / NN, j = e % NN;
        int cnt = cntS[r];
        double a = 0.0;
        for (int s2 = 0; s2 < cnt; ++s2)
          a = fma(wS[r][s2], G[idxS[r][s2] * NN + j], a);
        R[e] = a;
      }
      __syncthreads();
      // G = R * L^T
      for (int e = t; e < NN * NN; e += 512) {
        int r = e / NN, j = e % NN;
        int cnt = cntS[j];
        double a = 0.0;
        for (int s2 = 0; s2 < cnt; ++s2)
          a = fma(wS[j][s2], R[r * NN + idxS[j][s2]], a);
        G[e] = a;
      }
      __syncthreads();
    }

    if (hop == KHOP - 1) {
      // final gram out
      for (int e = t; e < NN * NN; e += 512) Gf[e] = G[e];
      __syncthreads();
      // ---- dense L^2 into G (sparse scatter, ascending k == round-5 order) ----
      if (t < NN) {
        for (int j = 0; j < NN; ++j) G[t * NN + j] = 0.0;
        int cnt = cntS[t];
        for (int s2 = 0; s2 < cnt; ++s2) {
          double w1 = wS[t][s2]; int k = idxS[t][s2];
          int c2 = cntS[k];
          for (int t2 = 0; t2 < c2; ++t2)
            G[t * NN + idxS[k][t2]] += w1 * wS[k][t2];
        }
      }
      __syncthreads();
      // ---- W = build_graph(build_graph(L^2)) ----
      for (int rep = 0; rep < 2; ++rep) {
        if (t < NN) G[t * NN + t] = 0.0;
        __syncthreads();
        if (t < NN) {
          double s = 0.0;
          for (int j = 0; j < NN; ++j) s += G[t * NN + j];
          Dsh[t] = 1.0 / sqrt(s);
        }
        __syncthreads();
        for (int e = t; e < NN * NN; e += 512) {
          int i = e / NN, j = e % NN;
          G[e] = (Dsh[j] * G[e]) * Dsh[i];
        }
        __syncthreads();
      }
      // M = I - 0.7*W
      for (int e = t; e < NN * NN; e += 512) {
        int i = e / NN, j = e % NN;
        G[e] = ((i == j) ? 1.0 : 0.0) - 0.7 * G[e];
      }
      __syncthreads();
      // ---- Gauss-Jordan sweep inverse in LDS ----
      for (int k = 0; k < NN; ++k) {
        if (t < NN) { rowk[t] = G[k * NN + t]; colk[t] = G[t * NN + k]; }
        __syncthreads();
        double pinv = 1.0 / rowk[k];
        for (int e = t; e < NN * NN; e += 512) {
          int i = e / NN, j = e % NN;
          double v;
          if (i == k)      v = (j == k) ? pinv : rowk[j] * pinv;
          else if (j == k) v = -(colk[i] * pinv);
          else             v = G[e] - colk[i] * (rowk[j] * pinv);
          G[e] = v;
        }
        __syncthreads();
      }
      for (int e = t; e < NN * NN; e += 512) Inv[e] = G[e];
    }
  }
}

// =====================================================================
// Kernel 2: unchanged from round 5 (validated) except episode offsets.
// =====================================================================
__global__ __launch_bounds__(256, 2) void k2_epochs(const int* __restrict__ ys,
                                                    const int* __restrict__ yq,
                                                    char* __restrict__ wsb,
                                                    float* __restrict__ out) {
  const int b = blockIdx.x;
  const double* G   = (const double*)(wsb + CTRL_BYTES) + (size_t)b * EP_DBL;
  const double* Inv = G + INV_OFF;
  unsigned* ctrlu = (unsigned*)wsb;

  __shared__ double Z[NN * WAYS];
  __shared__ double gvF[WAYS * NN];
  __shared__ double pbuf[4][WAYS * NN];
  __shared__ double betaS[WAYS][NN];
  __shared__ double nrmS[NN];
  __shared__ double csv[WAYS], pnS[WAYS];
  __shared__ int ysS[NSUP];
  __shared__ unsigned Tsh;
  __shared__ int redi;

  const int t  = threadIdx.x;
  const int wv = t >> 6, ln = t & 63;
  unsigned rnd = 0;

  if (t < NSUP) ysS[t] = ys[b * NSUP + t];
  if (t < NN)   nrmS[t] = G[t * NN + t];
  for (int e = t; e < WAYS * NN; e += 256) {
    int w = e / NN, n = e % NN;
    betaS[w][n] = (n >= w * 5 && n < w * 5 + 5) ? 0.2 : 0.0;
  }
  __syncthreads();

  auto sinkhorn = [&](int base, int n, double cval, bool clamp) {
    const bool own = (wv == 0);
    const int r0 = ln, r1 = ln + 64;
    const bool h1 = (r1 < n);
    double p0[WAYS], p1[WAYS];
    double up0 = 0.0, up1 = 0.0, u0 = 0.0, u1 = 0.0, dcur = 0.0;
    int m = 0; int ysq = -1;
    if (own) {
      #pragma unroll
      for (int w = 0; w < WAYS; ++w) {
        p0[w] = Z[(base + r0) * WAYS + w];
        p1[w] = h1 ? Z[(base + r1) * WAYS + w] : 0.0;
      }
      if (clamp && r0 < NSUP) ysq = ysS[r0];
      u0 = p0[0] + p0[1] + p0[2] + p0[3] + p0[4];
      if (h1) u1 = p1[0] + p1[1] + p1[2] + p1[3] + p1[4];
      double dl = fabs(up0 - u0);
      if (h1) dl = fmax(dl, fabs(up1 - u1));
      dcur = wmax64d(dl);
    }
    unsigned target = 0;
    for (;;) {
      if (own) {
        while (m < 1000 && ((unsigned)m < target || dcur > 1e-3)) {
          double i0 = 1.0 / u0;
          #pragma unroll
          for (int w = 0; w < WAYS; ++w) p0[w] *= i0;
          up0 = u0;
          if (h1) {
            double i1 = 1.0 / u1;
            #pragma unroll
            for (int w = 0; w < WAYS; ++w) p1[w] *= i1;
            up1 = u1;
          }
          #pragma unroll
          for (int w = 0; w < WAYS; ++w) {
            double s = wsum64d(p0[w] + (h1 ? p1[w] : 0.0));
            double f = cval / s;
            p0[w] *= f;
            if (h1) p1[w] *= f;
          }
          if (clamp && r0 < NSUP) {
            #pragma unroll
            for (int w = 0; w < WAYS; ++w) p0[w] = (ysq == w) ? 1.0 : 0.0;
          }
          ++m;
          u0 = p0[0] + p0[1] + p0[2] + p0[3] + p0[4];
          if (h1) u1 = p1[0] + p1[1] + p1[2] + p1[3] + p1[4];
          double dl = fabs(up0 - u0);
          if (h1) dl = fmax(dl, fabs(up1 - u1));
          dcur = wmax64d(dl);
        }
      }
      __syncthreads();
      if (t == 0) Tsh = grid_barrier_max(ctrlu, b, rnd, (unsigned)m);
      __syncthreads();
      ++rnd;
      unsigned T = Tsh;
      if (T == target) break;
      target = T;
    }
    if (own) {
      #pragma unroll
      for (int w = 0; w < WAYS; ++w) {
        Z[(base + r0) * WAYS + w] = p0[w];
        if (h1) Z[(base + r1) * WAYS + w] = p1[w];
      }
    }
    __syncthreads();
  };

  for (int epi = 0; epi <= NEPOCH; ++epi) {
    // gv[w][r] = sum_k G[r][k]*beta[w][k]  (k split over waves)
    {
      double a0[WAYS], a1[WAYS];
      #pragma unroll
      for (int w = 0; w < WAYS; ++w) { a0[w] = 0.0; a1[w] = 0.0; }
      int k0 = wv * 25;
      for (int kk = 0; kk < 25; ++kk) {
        int k = k0 + kk;
        double g0 = G[(size_t)k * NN + ln];
        double g1 = (ln < NN - 64) ? G[(size_t)k * NN + 64 + ln] : 0.0;
        #pragma unroll
        for (int w = 0; w < WAYS; ++w) {
          double bw = betaS[w][k];
          a0[w] = fma(g0, bw, a0[w]);
          a1[w] = fma(g1, bw, a1[w]);
        }
      }
      #pragma unroll
      for (int w = 0; w < WAYS; ++w) {
        pbuf[wv][w * NN + ln] = a0[w];
        if (ln < NN - 64) pbuf[wv][w * NN + 64 + ln] = a1[w];
      }
    }
    __syncthreads();
    for (int e = t; e < WAYS * NN; e += 256)
      gvF[e] = ((pbuf[0][e] + pbuf[1][e]) + pbuf[2][e]) + pbuf[3][e];
    __syncthreads();
    if (t < WAYS) {
      double s = 0.0;
      for (int n = 0; n < NN; ++n) s = fma(betaS[t][n], gvF[t * NN + n], s);
      pnS[t] = s;
    }
    __syncthreads();
    for (int e = t; e < NQ * WAYS; e += 256) {
      int r = NSUP + e / WAYS, w = e % WAYS;
      double d = (nrmS[r] + pnS[w]) - 2.0 * gvF[w * NN + r];
      Z[r * WAYS + w] = exp(-10.0 * (d > 0.0 ? d : 0.0));
    }
    __syncthreads();
    sinkhorn(NSUP, NQ, 15.0, false);

    if (epi == NEPOCH) {
      if (t == 0) redi = 0;
      __syncthreads();
      if (t < NQ) {
        int row = NSUP + t;
        double bv = Z[row * WAYS + 0]; int am = 0;
        #pragma unroll
        for (int w = 1; w < WAYS; ++w) {
          double v = Z[row * WAYS + w];
          if (v > bv) { bv = v; am = w; }
        }
        if (am == yq[b * NQ + t]) atomicAdd(&redi, 1);
      }
      __syncthreads();
      if (t == 0) out[b] = (float)((double)redi / 75.0);
    } else {
      if (t < NSUP) {
        #pragma unroll
        for (int w = 0; w < WAYS; ++w) Z[t * WAYS + w] = (ysS[t] == w) ? 1.0 : 0.0;
      }
      __syncthreads();
      for (int r = wv; r < NN; r += 4) {
        double a0 = 0, a1 = 0, a2 = 0, a3 = 0, a4 = 0;
        for (int k = ln; k < NN; k += 64) {
          double iv = Inv[(size_t)r * NN + k];
          a0 = fma(iv, Z[k * WAYS + 0], a0);
          a1 = fma(iv, Z[k * WAYS + 1], a1);
          a2 = fma(iv, Z[k * WAYS + 2], a2);
          a3 = fma(iv, Z[k * WAYS + 3], a3);
          a4 = fma(iv, Z[k * WAYS + 4], a4);
        }
        a0 = wsum64d(a0); a1 = wsum64d(a1); a2 = wsum64d(a2);
        a3 = wsum64d(a3); a4 = wsum64d(a4);
        if (ln == 0) {
          pbuf[0][r * WAYS + 0] = a0; pbuf[0][r * WAYS + 1] = a1;
          pbuf[0][r * WAYS + 2] = a2; pbuf[0][r * WAYS + 3] = a3;
          pbuf[0][r * WAYS + 4] = a4;
        }
      }
      __syncthreads();
      for (int e = t; e < NN * WAYS; e += 256) Z[e] = pbuf[0][e];
      __syncthreads();
      sinkhorn(0, NN, 20.0, true);
      if (t < WAYS) {
        double s = 0.0;
        for (int r = 0; r < NN; ++r) s += Z[r * WAYS + t];
        csv[t] = s;
      }
      __syncthreads();
      for (int e = t; e < NN * WAYS; e += 256) {
        int n = e / WAYS, w = e % WAYS;
        double nb = Z[n * WAYS + w] / csv[w];
        betaS[w][n] = 0.4 * betaS[w][n] + 0.6 * nb;
      }
      __syncthreads();
    }
  }
}

extern "C" void kernel_launch(void* const* d_in, const int* in_sizes, int n_in,
                              void* d_out, int out_size, void* d_ws, size_t ws_size,
                              hipStream_t stream) {
  const float* xs = (const float*)d_in[0];
  const float* xq = (const float*)d_in[1];
  const int*   ys = (const int*)d_in[2];
  const int*   yq = (const int*)d_in[3];
  float* out = (float*)d_out;
  char* ws   = (char*)d_ws;

  hipMemsetAsync(d_ws, 0, CTRL_BYTES, stream);

  (void)hipFuncSetAttribute((const void*)k1_lds,
                            hipFuncAttributeMaxDynamicSharedMemorySize,
                            DYN_LDS_BYTES);
  hipLaunchKernelGGL(k1_lds, dim3(B_RUNS), dim3(512), DYN_LDS_BYTES, stream, xs, xq, ws);
  hipLaunchKernelGGL(k2_epochs, dim3(B_RUNS), dim3(256), 0, stream, ys, yq, ws, out);
}